// Round 10
// baseline (267.093 us; speedup 1.0000x reference)
//
#include <hip/hip_runtime.h>

typedef unsigned short u16;
typedef unsigned int   u32;
typedef __bf16 bf16x8 __attribute__((ext_vector_type(8)));
typedef float  f32x4  __attribute__((ext_vector_type(4)));

#define S_LEN 4096
#define HIDN  2048
#define NHEAD 16
#define NKVH  4
#define HDIM  128
#define ROTD  64
#define QKVN  3072

__device__ __forceinline__ u16 f2bf(float f) {
  union { float f; u32 u; } v; v.f = f;
  u32 r = v.u + 0x7FFFu + ((v.u >> 16) & 1u);   // RNE
  return (u16)(r >> 16);
}
__device__ __forceinline__ u16 f2bf_fast(float f) {
  union { __bf16 b; u16 u; } cv; cv.b = (__bf16)f; return cv.u;   // v_cvt hw RNE
}
__device__ __forceinline__ float bf2f(u16 u) {
  union { u32 u; float f; } v; v.u = ((u32)u) << 16; return v.f;
}
__device__ __forceinline__ void gl2lds16(const u16* g, u16* l) {
  __builtin_amdgcn_global_load_lds((const __attribute__((address_space(1))) void*)g,
                                   (__attribute__((address_space(3))) void*)l, 16, 0, 0);
}
__device__ __forceinline__ f32x4 mfma_bf16(bf16x8 a, bf16x8 b, f32x4 c) {
  return __builtin_amdgcn_mfma_f32_16x16x32_bf16(a, b, c, 0, 0, 0);
}
template <int N> __device__ __forceinline__ void vmwait() {
  if constexpr (N == 7)      asm volatile("s_waitcnt vmcnt(7)" ::: "memory");
  else if constexpr (N == 6) asm volatile("s_waitcnt vmcnt(6)" ::: "memory");
  else                       asm volatile("s_waitcnt vmcnt(0)" ::: "memory");
}

// ---------------- f32 -> bf16 convert (8 elems/thread, exact grid) ----------
__global__ __launch_bounds__(256) void cvt_f32_bf16(const float* __restrict__ in,
                                                    u16* __restrict__ out) {
  size_t i = ((size_t)blockIdx.x * 256 + threadIdx.x) * 8;
  float4 a = *(const float4*)(in + i);
  float4 b = *(const float4*)(in + i + 4);
  uint4 r;
  r.x = (u32)f2bf(a.x) | ((u32)f2bf(a.y) << 16);
  r.y = (u32)f2bf(a.z) | ((u32)f2bf(a.w) << 16);
  r.z = (u32)f2bf(b.x) | ((u32)f2bf(b.y) << 16);
  r.w = (u32)f2bf(b.z) | ((u32)f2bf(b.w) << 16);
  *(uint4*)(out + i) = r;
}

// ---------------- GEMM v2: C[M,N] = A[M,K]*B[N,K]^T (unchanged from R9) -----
template <int BN, int NB, bool BF16OUT>
__global__ __launch_bounds__(512, 2) void gemm_big(const u16* __restrict__ A,
                                                   const u16* __restrict__ Bm,
                                                   void* __restrict__ Cp,
                                                   int M, int N, int K) {
  constexpr int WNC = BN / 4;
  constexpr int NF  = WNC / 16;
  constexpr int ASZ = 256 * 128;
  constexpr int BUF = ASZ + BN * 128;
  constexpr int LOADS = 4 + NB;
  __shared__ __align__(1024) char lds[2 * BUF];

  const int tid = threadIdx.x, wave = tid >> 6, lane = tid & 63;
  const int wm = wave >> 2, wn = wave & 3;
  const int row0 = blockIdx.x * 256, col0 = blockIdx.y * BN;
  const int l8 = lane >> 3, l7 = lane & 7;
  const int T = K >> 6;

  const u16* gA[4]; const u16* gB[NB];
  u16* ldsA[4]; u16* ldsB[NB];
  #pragma unroll
  for (int i = 0; i < 4; ++i) {
    gA[i]  = A + (size_t)(row0 + wave * 32 + i * 8 + l8) * K + (l7 ^ l8) * 8;
    ldsA[i] = (u16*)(lds + wave * 4096 + i * 1024);
  }
  #pragma unroll
  for (int i = 0; i < NB; ++i) {
    gB[i]  = Bm + (size_t)(col0 + wave * (BN / 8) + i * 8 + l8) * K + (l7 ^ l8) * 8;
    ldsB[i] = (u16*)(lds + ASZ + wave * (BN * 16) + i * 1024);
  }
  auto stage = [&](int buf, int t) {
    const size_t ko = (size_t)t * 64;
    #pragma unroll
    for (int i = 0; i < 4; ++i)
      gl2lds16(gA[i] + ko, (u16*)((char*)ldsA[i] + buf * BUF));
    #pragma unroll
    for (int i = 0; i < NB; ++i)
      gl2lds16(gB[i] + ko, (u16*)((char*)ldsB[i] + buf * BUF));
  };

  const int colx0 = (((lane >> 4))     ^ l7) * 16;
  const int colx1 = ((4 + (lane >> 4)) ^ l7) * 16;
  const char* aB = lds + (wm * 128 + (lane & 15)) * 128;
  const char* bB = lds + ASZ + (wn * WNC + (lane & 15)) * 128;

  f32x4 acc[8][NF];
  #pragma unroll
  for (int i = 0; i < 8; ++i)
    #pragma unroll
    for (int j = 0; j < NF; ++j) { f32x4 z = {0.f,0.f,0.f,0.f}; acc[i][j] = z; }

  stage(0, 0);
  stage(1, 1);
  vmwait<LOADS>();
  __builtin_amdgcn_s_barrier();

  for (int t = 0; t < T; ++t) {
    const int bo = (t & 1) * BUF;
    #pragma unroll
    for (int kh = 0; kh < 2; ++kh) {
      const int cx = kh ? colx1 : colx0;
      bf16x8 bfr[NF];
      #pragma unroll
      for (int nf = 0; nf < NF; ++nf)
        bfr[nf] = *(const bf16x8*)(bB + bo + nf * 2048 + cx);
      #pragma unroll
      for (int mh = 0; mh < 2; ++mh) {
        bf16x8 af[4];
        #pragma unroll
        for (int mf = 0; mf < 4; ++mf)
          af[mf] = *(const bf16x8*)(aB + bo + mh * 8192 + mf * 2048 + cx);
        __builtin_amdgcn_s_setprio(1);
        #pragma unroll
        for (int mf = 0; mf < 4; ++mf)
          #pragma unroll
          for (int nf = 0; nf < NF; ++nf)
            acc[mh * 4 + mf][nf] = mfma_bf16(af[mf], bfr[nf], acc[mh * 4 + mf][nf]);
        __builtin_amdgcn_s_setprio(0);
      }
    }
    asm volatile("s_waitcnt lgkmcnt(0)" ::: "memory");
    __builtin_amdgcn_s_barrier();
    if (t + 2 < T) stage(t & 1, t + 2);
    if (t + 1 < T) {
      if (t + 2 < T) vmwait<LOADS>();
      else           vmwait<0>();
      __builtin_amdgcn_s_barrier();
    }
  }

  const int mwv = row0 + wm * 128, nwv = col0 + wn * WNC;
  #pragma unroll
  for (int mf8 = 0; mf8 < 8; ++mf8)
    #pragma unroll
    for (int nf = 0; nf < NF; ++nf)
      #pragma unroll
      for (int r = 0; r < 4; ++r) {
        int m = mwv + (mf8 >> 2) * 64 + (mf8 & 3) * 16 + (lane >> 4) * 4 + r;
        int n = nwv + nf * 16 + (lane & 15);
        float v = acc[mf8][nf][r];
        if (BF16OUT) ((u16*)Cp)[(size_t)m * N + n] = f2bf(v);
        else         ((float*)Cp)[(size_t)m * N + n] = v;
      }
}

// ---------------- fused RMSNorm (full row) + partial RoPE + head transpose --
__global__ __launch_bounds__(256) void norm_rope(const u16* __restrict__ qkv,
                                                 const float* __restrict__ cosb,
                                                 const float* __restrict__ sinb,
                                                 const float* __restrict__ qw,
                                                 const float* __restrict__ kw,
                                                 u16* __restrict__ Qo,
                                                 u16* __restrict__ Ko) {
  const int s = blockIdx.x, t = threadIdx.x;
  const int wave = t >> 6, lane = t & 63;
  const float SL = 0.08838834764831845f * 1.4426950408889634f;  // SCALE*log2e
  __shared__ float rowbuf[HIDN];
  __shared__ float red[4];
  const u16* base = qkv + (size_t)s * QKVN;

  float x[8];
  {
    uint4 v = *(const uint4*)(base + t * 8);
    u32 w4[4] = {v.x, v.y, v.z, v.w};
    #pragma unroll
    for (int j = 0; j < 4; ++j) {
      x[2*j]   = bf2f((u16)(w4[j] & 0xffffu));
      x[2*j+1] = bf2f((u16)(w4[j] >> 16));
    }
  }
  float ss = 0.f;
  #pragma unroll
  for (int j = 0; j < 8; ++j) ss += x[j] * x[j];
  #pragma unroll
  for (int m = 1; m < 64; m <<= 1) ss += __shfl_xor(ss, m);
  if (lane == 0) red[wave] = ss;
  __syncthreads();
  float rs = rsqrtf((red[0]+red[1]+red[2]+red[3]) * (1.0f / HIDN) + 1e-6f);
  #pragma unroll
  for (int j = 0; j < 8; ++j) rowbuf[t*8 + j] = x[j] * rs * qw[t*8 + j];
  __syncthreads();
  {
    int i0 = t * 8, d0 = i0 & (HDIM - 1), hh = i0 >> 7;
    float o[8];
    if (d0 < ROTD) {
      #pragma unroll
      for (int j = 0; j < 8; ++j) {
        int d = d0 + j;
        float rot = (d < 32) ? -rowbuf[i0 + j + 32] : rowbuf[i0 + j - 32];
        o[j] = rowbuf[i0 + j] * cosb[s*ROTD + d] + rot * sinb[s*ROTD + d];
      }
    } else {
      #pragma unroll
      for (int j = 0; j < 8; ++j) o[j] = rowbuf[i0 + j];
    }
    uint4 r;
    r.x = (u32)f2bf(o[0]*SL) | ((u32)f2bf(o[1]*SL) << 16);
    r.y = (u32)f2bf(o[2]*SL) | ((u32)f2bf(o[3]*SL) << 16);
    r.z = (u32)f2bf(o[4]*SL) | ((u32)f2bf(o[5]*SL) << 16);
    r.w = (u32)f2bf(o[6]*SL) | ((u32)f2bf(o[7]*SL) << 16);
    *(uint4*)(Qo + ((size_t)hh * S_LEN + s) * HDIM + d0) = r;
  }

  const u16* kbase = base + HIDN;
  float y0, y1;
  { u32 v = *(const u32*)(kbase + t * 2); y0 = bf2f((u16)(v & 0xffffu)); y1 = bf2f((u16)(v >> 16)); }
  float ss2 = y0*y0 + y1*y1;
  #pragma unroll
  for (int m = 1; m < 64; m <<= 1) ss2 += __shfl_xor(ss2, m);
  __syncthreads();
  if (lane == 0) red[wave] = ss2;
  __syncthreads();
  float rs2 = rsqrtf((red[0]+red[1]+red[2]+red[3]) * (1.0f / 512.0f) + 1e-6f);
  rowbuf[t*2]     = y0 * rs2 * kw[t*2];
  rowbuf[t*2 + 1] = y1 * rs2 * kw[t*2 + 1];
  __syncthreads();
  {
    int i0 = t * 2, d0 = i0 & (HDIM - 1), hh = i0 >> 7;
    float o0, o1;
    if (d0 < ROTD) {
      float r0 = (d0 < 32) ? -rowbuf[i0 + 32] : rowbuf[i0 - 32];
      float r1 = (d0 + 1 < 32) ? -rowbuf[i0 + 1 + 32] : rowbuf[i0 + 1 - 32];
      o0 = rowbuf[i0]     * cosb[s*ROTD + d0]     + r0 * sinb[s*ROTD + d0];
      o1 = rowbuf[i0 + 1] * cosb[s*ROTD + d0 + 1] + r1 * sinb[s*ROTD + d0 + 1];
    } else { o0 = rowbuf[i0]; o1 = rowbuf[i0 + 1]; }
    u32 r = (u32)f2bf(o0) | ((u32)f2bf(o1) << 16);
    *(u32*)(Ko + ((size_t)hh * S_LEN + s) * HDIM + d0) = r;
  }
}

// ---------------- V transpose: qkv[S][3072] v-cols -> Vt[NKV][HD][S] --------
__global__ __launch_bounds__(256) void vtrans(const u16* __restrict__ qkv,
                                              u16* __restrict__ Vt) {
  const int sb = blockIdx.x * 64, db = blockIdx.y * 64, kvh = blockIdx.z;
  __shared__ u16 tile[64][72];
  const int t = threadIdx.x;
  {
    int r = t >> 2, cc = (t & 3) * 16;
    const u16* src = qkv + (size_t)(sb + r) * QKVN + 2560 + kvh * HDIM + db + cc;
    *(uint4*)&tile[r][cc]     = *(const uint4*)(src);
    *(uint4*)&tile[r][cc + 8] = *(const uint4*)(src + 8);
  }
  __syncthreads();
  {
    int d = t >> 2, sc = (t & 3) * 16;
    u16 tmp[16];
    #pragma unroll
    for (int j = 0; j < 16; ++j) tmp[j] = tile[sc + j][d];
    u16* dst = Vt + ((size_t)kvh * HDIM + db + d) * S_LEN + sb + sc;
    *(uint4*)dst       = *(uint4*)&tmp[0];
    *(uint4*)(dst + 8) = *(uint4*)&tmp[8];
  }
}

// ---------------- causal GQA flash attention (v6) ---------------------------
// GQA head-pair sharing: one block = 2 heads of the same kvh group.
// Waves 0-1 -> head h0, waves 2-3 -> h1; each wave 32 q rows (2 M-frags).
// K/V staged ONCE per block feeds both heads -> LDS bytes per flop HALVED
// vs v5 (each kf/vf read feeds 2 MFMAs; total grid tiles halved at same
// per-tile LDS cost). Geometry stays balanced: 64-row q-tiles, mirror-paired
// jobs (qb=p, 63-p) = uniform 65 tiles/block; 256 blocks x 256 thr, 80KB LDS
// -> exactly 2 blocks/CU, all resident, tail-free.
// Static-max softmax (RMSNorm-bounded scores), Q pre-scaled by SCALE*log2e,
// XCD affinity: slot=bid&7 -> kvh=slot>>1 (2MB K+V per XCD L2).
__global__ __launch_bounds__(256, 2) void attn_fwd(const u16* __restrict__ Q,
                                                   const u16* __restrict__ K,
                                                   const u16* __restrict__ Vt,
                                                   u16* __restrict__ O) {
  const int bid  = blockIdx.x;
  const int slot = bid & 7, p = bid >> 3;          // p = mirror-pair 0..31
  const int kvh  = slot >> 1, hp = slot & 1;
  const int tid = threadIdx.x, wave = tid >> 6, lane = tid & 63;
  const int h  = kvh * 4 + hp * 2 + (wave >> 1);   // per-wave head
  const int wq = wave & 1;                         // row-half within q-tile
  __shared__ u16 Ks[2][64][128];                   // 32KB
  __shared__ u16 Vs[2][128][64];                   // 32KB
  __shared__ u16 Ps[4][32][64];                    // 16KB

  // block-level staging bases (pre-swizzled global source)
  const u16* gKb[4]; const u16* gVb[4];
  #pragma unroll
  for (int i = 0; i < 4; ++i) {
    int cc = wave * 4 + i;
    int rk = cc * 4 + (lane >> 4);
    gKb[i] = K + ((size_t)kvh * S_LEN + rk) * HDIM + ((lane & 15) ^ (rk & 7)) * 8;
    int rv = cc * 8 + (lane >> 3);
    gVb[i] = Vt + ((size_t)kvh * HDIM + rv) * S_LEN + ((lane & 7) ^ (rv & 7)) * 8;
  }
  auto stage = [&](int buf, int kvb) {
    #pragma unroll
    for (int i = 0; i < 4; ++i) {
      int cc = wave * 4 + i;
      gl2lds16(gKb[i] + (size_t)kvb * HDIM, &Ks[buf][cc * 4][0]);
      gl2lds16(gVb[i] + kvb,                &Vs[buf][cc * 8][0]);
    }
  };

  // swizzled LDS read offsets ((row&7) == (lane&7) for every fragment read)
  int offv[4];
  #pragma unroll
  for (int kk = 0; kk < 4; ++kk)
    offv[kk] = (kk * 64 + (lane >> 4) * 16) ^ ((lane & 7) << 4);
  const char* ksB = (const char*)Ks + (lane & 15) * 256;
  const char* vsB = (const char*)Vs + (lane & 15) * 128;
  const char* psB = (const char*)Ps + wave * 4096 + (lane & 15) * 128;
  char*       pwB = (char*)Ps + wave * 4096;
  const int   lx2 = (lane & 15) * 2;

  stage(0, 0);                                     // prologue: job0 tile0
  __syncthreads();
  int cur = 0;

  for (int job = 0; job < 2; ++job) {
    const int qb = job ? (63 - p) : p;
    const int ntiles = qb + 1;
    const int qg0 = qb * 64 + wq * 32 + (lane >> 4) * 4;  // + qm*16 + r = q row

    // Q fragments: 2 M-frags x 4 k-slices (per-wave head, per-wave row half)
    bf16x8 qf[2][4];
    #pragma unroll
    for (int qm = 0; qm < 2; ++qm) {
      const u16* qptr = Q + ((size_t)h * S_LEN + qb * 64 + wq * 32 + qm * 16 + (lane & 15)) * HDIM
                        + (lane >> 4) * 8;
      #pragma unroll
      for (int kk = 0; kk < 4; ++kk) qf[qm][kk] = *(const bf16x8*)(qptr + kk * 32);
    }

    float lsum[2][4];
    #pragma unroll
    for (int qm = 0; qm < 2; ++qm)
      #pragma unroll
      for (int r = 0; r < 4; ++r) lsum[qm][r] = 0.f;
    f32x4 o[2][8];
    #pragma unroll
    for (int qm = 0; qm < 2; ++qm)
      #pragma unroll
      for (int i = 0; i < 8; ++i) { f32x4 z = {0.f,0.f,0.f,0.f}; o[qm][i] = z; }

    for (int kt = 0; kt < ntiles; ++kt) {
      // ---- prefetch next tile (this job's kt+1, or job1's tile 0) ----
      if (kt + 1 < ntiles)      stage(cur ^ 1, (kt + 1) * 64);
      else if (job == 0)        stage(cur ^ 1, 0);

      const int bufo = cur << 14;                  // 16KB per K/V buffer half

      // ---- QK^T: each kf feeds both M-frags ----
      f32x4 sc[2][4];
      #pragma unroll
      for (int qm = 0; qm < 2; ++qm)
        #pragma unroll
        for (int i = 0; i < 4; ++i) { f32x4 z = {0.f,0.f,0.f,0.f}; sc[qm][i] = z; }
      __builtin_amdgcn_s_setprio(1);
      #pragma unroll
      for (int kk = 0; kk < 4; ++kk)
        #pragma unroll
        for (int nf = 0; nf < 4; ++nf) {
          bf16x8 kf = *(const bf16x8*)(ksB + bufo + nf * 4096 + offv[kk]);
          sc[0][nf] = mfma_bf16(qf[0][kk], kf, sc[0][nf]);
          sc[1][nf] = mfma_bf16(qf[1][kk], kf, sc[1][nf]);
        }
      __builtin_amdgcn_s_setprio(0);

      // ---- static-max softmax: e = 2^s directly; zero-mask on diag tile ----
      if (kt == ntiles - 1) {
        const int kvb = kt * 64;
        #pragma unroll
        for (int qm = 0; qm < 2; ++qm)
          #pragma unroll
          for (int nf = 0; nf < 4; ++nf) {
            int col = kvb + nf * 16 + (lane & 15);
            #pragma unroll
            for (int r = 0; r < 4; ++r) {
              float e = __builtin_amdgcn_exp2f(sc[qm][nf][r]);
              e = (col <= qg0 + qm * 16 + r) ? e : 0.f;
              sc[qm][nf][r] = e;
              lsum[qm][r] += e;
            }
          }
      } else {
        #pragma unroll
        for (int qm = 0; qm < 2; ++qm)
          #pragma unroll
          for (int nf = 0; nf < 4; ++nf)
            #pragma unroll
            for (int r = 0; r < 4; ++r) {
              float e = __builtin_amdgcn_exp2f(sc[qm][nf][r]);
              sc[qm][nf][r] = e;
              lsum[qm][r] += e;
            }
      }

      // ---- P write (swizzled; prow&7 unaffected by qm*16) ----
      #pragma unroll
      for (int qm = 0; qm < 2; ++qm)
        #pragma unroll
        for (int nf = 0; nf < 4; ++nf)
          #pragma unroll
          for (int r = 0; r < 4; ++r) {
            int prow = qm * 16 + (lane >> 4) * 4 + r;
            int bcol = (nf * 32 + lx2) ^ ((prow & 7) << 4);
            *(u16*)(pwB + prow * 128 + bcol) = f2bf_fast(sc[qm][nf][r]);
          }

      // ---- PV: each vf feeds both M-frags ----
      __builtin_amdgcn_s_setprio(1);
      #pragma unroll
      for (int ks = 0; ks < 2; ++ks) {
        bf16x8 pf0 = *(const bf16x8*)(psB + offv[ks]);
        bf16x8 pf1 = *(const bf16x8*)(psB + 2048 + offv[ks]);
        #pragma unroll
        for (int nf2 = 0; nf2 < 8; ++nf2) {
          bf16x8 vf = *(const bf16x8*)(vsB + bufo + nf2 * 2048 + offv[ks]);
          o[0][nf2] = mfma_bf16(pf0, vf, o[0][nf2]);
          o[1][nf2] = mfma_bf16(pf1, vf, o[1][nf2]);
        }
      }
      __builtin_amdgcn_s_setprio(0);

      __syncthreads();                             // staged buf ready, cur reusable
      cur ^= 1;
    }

    // ---- epilogue: reduce lane-local lsum across the 16-lane row group ----
    #pragma unroll
    for (int qm = 0; qm < 2; ++qm)
      #pragma unroll
      for (int r = 0; r < 4; ++r) {
        float lt = lsum[qm][r];
        #pragma unroll
        for (int m = 1; m < 16; m <<= 1) lt += __shfl_xor(lt, m);
        float inv = 1.f / lt;
        int srow = qg0 + qm * 16 + r;
        #pragma unroll
        for (int nf2 = 0; nf2 < 8; ++nf2) {
          int col = h * HDIM + nf2 * 16 + (lane & 15);
          O[(size_t)srow * HIDN + col] = f2bf_fast(o[qm][nf2][r] * inv);
        }
      }
  }
}

// ---------------- launch -----------------------------------------------------
extern "C" void kernel_launch(void* const* d_in, const int* in_sizes, int n_in,
                              void* d_out, int out_size, void* d_ws, size_t ws_size,
                              hipStream_t stream) {
  (void)in_sizes; (void)n_in; (void)out_size; (void)ws_size;
  const float* h    = (const float*)d_in[0];
  const float* cosb = (const float*)d_in[1];
  const float* sinb = (const float*)d_in[2];
  const float* Wq   = (const float*)d_in[3];
  const float* Wk   = (const float*)d_in[4];
  const float* Wv   = (const float*)d_in[5];
  const float* Wo   = (const float*)d_in[6];
  const float* qw   = (const float*)d_in[7];
  const float* kw   = (const float*)d_in[8];
  float* out = (float*)d_out;

  char* ws = (char*)d_ws;
  u16* hbf  = (u16*)(ws);
  u16* Kb   = (u16*)(ws + (16u << 20));
  u16* Vtb  = (u16*)(ws + (20u << 20));
  u16* wqkv = (u16*)(ws + (24u << 20));
  u16* Qb   = (u16*)(ws + (24u << 20));
  u16* qkvb = (u16*)(ws + (40u << 20));
  u16* wob  = (u16*)(ws + (40u << 20));

  cvt_f32_bf16<<<4096, 256, 0, stream>>>(h, hbf);
  cvt_f32_bf16<<<2048, 256, 0, stream>>>(Wq, wqkv);
  cvt_f32_bf16<<<512, 256, 0, stream>>>(Wk, wqkv + 4u * 1024 * 1024);
  cvt_f32_bf16<<<512, 256, 0, stream>>>(Wv, wqkv + 5u * 1024 * 1024);

  gemm_big<192, 3, true><<<dim3(16, 16), 512, 0, stream>>>(hbf, wqkv, qkvb,
                                                           4096, 3072, 2048);

  norm_rope<<<4096, 256, 0, stream>>>(qkvb, cosb, sinb, qw, kw, Qb, Kb);
  vtrans<<<dim3(64, 2, 4), 256, 0, stream>>>(qkvb, Vtb);

  cvt_f32_bf16<<<2048, 256, 0, stream>>>(Wo, wob);

  attn_fwd<<<dim3(256), 256, 0, stream>>>(Qb, Kb, Vtb, hbf);

  gemm_big<128, 2, false><<<dim3(16, 16), 512, 0, stream>>>(hbf, wob, out,
                                                            4096, 2048, 2048);
}

// Round 11
// 266.903 us; speedup vs baseline: 1.0007x; 1.0007x over previous
//
#include <hip/hip_runtime.h>

typedef unsigned short u16;
typedef unsigned int   u32;
typedef __bf16 bf16x8 __attribute__((ext_vector_type(8)));
typedef float  f32x4  __attribute__((ext_vector_type(4)));

#define S_LEN 4096
#define HIDN  2048
#define NHEAD 16
#define NKVH  4
#define HDIM  128
#define ROTD  64
#define QKVN  3072

__device__ __forceinline__ u16 f2bf(float f) {
  union { float f; u32 u; } v; v.f = f;
  u32 r = v.u + 0x7FFFu + ((v.u >> 16) & 1u);   // RNE
  return (u16)(r >> 16);
}
__device__ __forceinline__ u16 f2bf_fast(float f) {
  union { __bf16 b; u16 u; } cv; cv.b = (__bf16)f; return cv.u;   // v_cvt hw RNE
}
__device__ __forceinline__ float bf2f(u16 u) {
  union { u32 u; float f; } v; v.u = ((u32)u) << 16; return v.f;
}
__device__ __forceinline__ void gl2lds16(const u16* g, u16* l) {
  __builtin_amdgcn_global_load_lds((const __attribute__((address_space(1))) void*)g,
                                   (__attribute__((address_space(3))) void*)l, 16, 0, 0);
}
__device__ __forceinline__ f32x4 mfma_bf16(bf16x8 a, bf16x8 b, f32x4 c) {
  return __builtin_amdgcn_mfma_f32_16x16x32_bf16(a, b, c, 0, 0, 0);
}
template <int N> __device__ __forceinline__ void vmwait() {
  if constexpr (N == 7)      asm volatile("s_waitcnt vmcnt(7)" ::: "memory");
  else if constexpr (N == 6) asm volatile("s_waitcnt vmcnt(6)" ::: "memory");
  else                       asm volatile("s_waitcnt vmcnt(0)" ::: "memory");
}

// ---------------- f32 -> bf16 convert (8 elems/thread, exact grid) ----------
__global__ __launch_bounds__(256) void cvt_f32_bf16(const float* __restrict__ in,
                                                    u16* __restrict__ out) {
  size_t i = ((size_t)blockIdx.x * 256 + threadIdx.x) * 8;
  float4 a = *(const float4*)(in + i);
  float4 b = *(const float4*)(in + i + 4);
  uint4 r;
  r.x = (u32)f2bf(a.x) | ((u32)f2bf(a.y) << 16);
  r.y = (u32)f2bf(a.z) | ((u32)f2bf(a.w) << 16);
  r.z = (u32)f2bf(b.x) | ((u32)f2bf(b.y) << 16);
  r.w = (u32)f2bf(b.z) | ((u32)f2bf(b.w) << 16);
  *(uint4*)(out + i) = r;
}

// ---------------- GEMM v2: C[M,N] = A[M,K]*B[N,K]^T (unchanged from R9) -----
template <int BN, int NB, bool BF16OUT>
__global__ __launch_bounds__(512, 2) void gemm_big(const u16* __restrict__ A,
                                                   const u16* __restrict__ Bm,
                                                   void* __restrict__ Cp,
                                                   int M, int N, int K) {
  constexpr int WNC = BN / 4;
  constexpr int NF  = WNC / 16;
  constexpr int ASZ = 256 * 128;
  constexpr int BUF = ASZ + BN * 128;
  constexpr int LOADS = 4 + NB;
  __shared__ __align__(1024) char lds[2 * BUF];

  const int tid = threadIdx.x, wave = tid >> 6, lane = tid & 63;
  const int wm = wave >> 2, wn = wave & 3;
  const int row0 = blockIdx.x * 256, col0 = blockIdx.y * BN;
  const int l8 = lane >> 3, l7 = lane & 7;
  const int T = K >> 6;

  const u16* gA[4]; const u16* gB[NB];
  u16* ldsA[4]; u16* ldsB[NB];
  #pragma unroll
  for (int i = 0; i < 4; ++i) {
    gA[i]  = A + (size_t)(row0 + wave * 32 + i * 8 + l8) * K + (l7 ^ l8) * 8;
    ldsA[i] = (u16*)(lds + wave * 4096 + i * 1024);
  }
  #pragma unroll
  for (int i = 0; i < NB; ++i) {
    gB[i]  = Bm + (size_t)(col0 + wave * (BN / 8) + i * 8 + l8) * K + (l7 ^ l8) * 8;
    ldsB[i] = (u16*)(lds + ASZ + wave * (BN * 16) + i * 1024);
  }
  auto stage = [&](int buf, int t) {
    const size_t ko = (size_t)t * 64;
    #pragma unroll
    for (int i = 0; i < 4; ++i)
      gl2lds16(gA[i] + ko, (u16*)((char*)ldsA[i] + buf * BUF));
    #pragma unroll
    for (int i = 0; i < NB; ++i)
      gl2lds16(gB[i] + ko, (u16*)((char*)ldsB[i] + buf * BUF));
  };

  const int colx0 = (((lane >> 4))     ^ l7) * 16;
  const int colx1 = ((4 + (lane >> 4)) ^ l7) * 16;
  const char* aB = lds + (wm * 128 + (lane & 15)) * 128;
  const char* bB = lds + ASZ + (wn * WNC + (lane & 15)) * 128;

  f32x4 acc[8][NF];
  #pragma unroll
  for (int i = 0; i < 8; ++i)
    #pragma unroll
    for (int j = 0; j < NF; ++j) { f32x4 z = {0.f,0.f,0.f,0.f}; acc[i][j] = z; }

  stage(0, 0);
  stage(1, 1);
  vmwait<LOADS>();
  __builtin_amdgcn_s_barrier();

  for (int t = 0; t < T; ++t) {
    const int bo = (t & 1) * BUF;
    #pragma unroll
    for (int kh = 0; kh < 2; ++kh) {
      const int cx = kh ? colx1 : colx0;
      bf16x8 bfr[NF];
      #pragma unroll
      for (int nf = 0; nf < NF; ++nf)
        bfr[nf] = *(const bf16x8*)(bB + bo + nf * 2048 + cx);
      #pragma unroll
      for (int mh = 0; mh < 2; ++mh) {
        bf16x8 af[4];
        #pragma unroll
        for (int mf = 0; mf < 4; ++mf)
          af[mf] = *(const bf16x8*)(aB + bo + mh * 8192 + mf * 2048 + cx);
        __builtin_amdgcn_s_setprio(1);
        #pragma unroll
        for (int mf = 0; mf < 4; ++mf)
          #pragma unroll
          for (int nf = 0; nf < NF; ++nf)
            acc[mh * 4 + mf][nf] = mfma_bf16(af[mf], bfr[nf], acc[mh * 4 + mf][nf]);
        __builtin_amdgcn_s_setprio(0);
      }
    }
    asm volatile("s_waitcnt lgkmcnt(0)" ::: "memory");
    __builtin_amdgcn_s_barrier();
    if (t + 2 < T) stage(t & 1, t + 2);
    if (t + 1 < T) {
      if (t + 2 < T) vmwait<LOADS>();
      else           vmwait<0>();
      __builtin_amdgcn_s_barrier();
    }
  }

  const int mwv = row0 + wm * 128, nwv = col0 + wn * WNC;
  #pragma unroll
  for (int mf8 = 0; mf8 < 8; ++mf8)
    #pragma unroll
    for (int nf = 0; nf < NF; ++nf)
      #pragma unroll
      for (int r = 0; r < 4; ++r) {
        int m = mwv + (mf8 >> 2) * 64 + (mf8 & 3) * 16 + (lane >> 4) * 4 + r;
        int n = nwv + nf * 16 + (lane & 15);
        float v = acc[mf8][nf][r];
        if (BF16OUT) ((u16*)Cp)[(size_t)m * N + n] = f2bf(v);
        else         ((float*)Cp)[(size_t)m * N + n] = v;
      }
}

// ---------------- fused RMSNorm (full row) + partial RoPE + head transpose --
__global__ __launch_bounds__(256) void norm_rope(const u16* __restrict__ qkv,
                                                 const float* __restrict__ cosb,
                                                 const float* __restrict__ sinb,
                                                 const float* __restrict__ qw,
                                                 const float* __restrict__ kw,
                                                 u16* __restrict__ Qo,
                                                 u16* __restrict__ Ko) {
  const int s = blockIdx.x, t = threadIdx.x;
  const int wave = t >> 6, lane = t & 63;
  const float SL = 0.08838834764831845f * 1.4426950408889634f;  // SCALE*log2e
  __shared__ float rowbuf[HIDN];
  __shared__ float red[4];
  const u16* base = qkv + (size_t)s * QKVN;

  float x[8];
  {
    uint4 v = *(const uint4*)(base + t * 8);
    u32 w4[4] = {v.x, v.y, v.z, v.w};
    #pragma unroll
    for (int j = 0; j < 4; ++j) {
      x[2*j]   = bf2f((u16)(w4[j] & 0xffffu));
      x[2*j+1] = bf2f((u16)(w4[j] >> 16));
    }
  }
  float ss = 0.f;
  #pragma unroll
  for (int j = 0; j < 8; ++j) ss += x[j] * x[j];
  #pragma unroll
  for (int m = 1; m < 64; m <<= 1) ss += __shfl_xor(ss, m);
  if (lane == 0) red[wave] = ss;
  __syncthreads();
  float rs = rsqrtf((red[0]+red[1]+red[2]+red[3]) * (1.0f / HIDN) + 1e-6f);
  #pragma unroll
  for (int j = 0; j < 8; ++j) rowbuf[t*8 + j] = x[j] * rs * qw[t*8 + j];
  __syncthreads();
  {
    int i0 = t * 8, d0 = i0 & (HDIM - 1), hh = i0 >> 7;
    float o[8];
    if (d0 < ROTD) {
      #pragma unroll
      for (int j = 0; j < 8; ++j) {
        int d = d0 + j;
        float rot = (d < 32) ? -rowbuf[i0 + j + 32] : rowbuf[i0 + j - 32];
        o[j] = rowbuf[i0 + j] * cosb[s*ROTD + d] + rot * sinb[s*ROTD + d];
      }
    } else {
      #pragma unroll
      for (int j = 0; j < 8; ++j) o[j] = rowbuf[i0 + j];
    }
    uint4 r;
    r.x = (u32)f2bf(o[0]*SL) | ((u32)f2bf(o[1]*SL) << 16);
    r.y = (u32)f2bf(o[2]*SL) | ((u32)f2bf(o[3]*SL) << 16);
    r.z = (u32)f2bf(o[4]*SL) | ((u32)f2bf(o[5]*SL) << 16);
    r.w = (u32)f2bf(o[6]*SL) | ((u32)f2bf(o[7]*SL) << 16);
    *(uint4*)(Qo + ((size_t)hh * S_LEN + s) * HDIM + d0) = r;
  }

  const u16* kbase = base + HIDN;
  float y0, y1;
  { u32 v = *(const u32*)(kbase + t * 2); y0 = bf2f((u16)(v & 0xffffu)); y1 = bf2f((u16)(v >> 16)); }
  float ss2 = y0*y0 + y1*y1;
  #pragma unroll
  for (int m = 1; m < 64; m <<= 1) ss2 += __shfl_xor(ss2, m);
  __syncthreads();
  if (lane == 0) red[wave] = ss2;
  __syncthreads();
  float rs2 = rsqrtf((red[0]+red[1]+red[2]+red[3]) * (1.0f / 512.0f) + 1e-6f);
  rowbuf[t*2]     = y0 * rs2 * kw[t*2];
  rowbuf[t*2 + 1] = y1 * rs2 * kw[t*2 + 1];
  __syncthreads();
  {
    int i0 = t * 2, d0 = i0 & (HDIM - 1), hh = i0 >> 7;
    float o0, o1;
    if (d0 < ROTD) {
      float r0 = (d0 < 32) ? -rowbuf[i0 + 32] : rowbuf[i0 - 32];
      float r1 = (d0 + 1 < 32) ? -rowbuf[i0 + 1 + 32] : rowbuf[i0 + 1 - 32];
      o0 = rowbuf[i0]     * cosb[s*ROTD + d0]     + r0 * sinb[s*ROTD + d0];
      o1 = rowbuf[i0 + 1] * cosb[s*ROTD + d0 + 1] + r1 * sinb[s*ROTD + d0 + 1];
    } else { o0 = rowbuf[i0]; o1 = rowbuf[i0 + 1]; }
    u32 r = (u32)f2bf(o0) | ((u32)f2bf(o1) << 16);
    *(u32*)(Ko + ((size_t)hh * S_LEN + s) * HDIM + d0) = r;
  }
}

// ---------------- V transpose: qkv[S][3072] v-cols -> Vt[NKV][HD][S] --------
__global__ __launch_bounds__(256) void vtrans(const u16* __restrict__ qkv,
                                              u16* __restrict__ Vt) {
  const int sb = blockIdx.x * 64, db = blockIdx.y * 64, kvh = blockIdx.z;
  __shared__ u16 tile[64][72];
  const int t = threadIdx.x;
  {
    int r = t >> 2, cc = (t & 3) * 16;
    const u16* src = qkv + (size_t)(sb + r) * QKVN + 2560 + kvh * HDIM + db + cc;
    *(uint4*)&tile[r][cc]     = *(const uint4*)(src);
    *(uint4*)&tile[r][cc + 8] = *(const uint4*)(src + 8);
  }
  __syncthreads();
  {
    int d = t >> 2, sc = (t & 3) * 16;
    u16 tmp[16];
    #pragma unroll
    for (int j = 0; j < 16; ++j) tmp[j] = tile[sc + j][d];
    u16* dst = Vt + ((size_t)kvh * HDIM + db + d) * S_LEN + sb + sc;
    *(uint4*)dst       = *(uint4*)&tmp[0];
    *(uint4*)(dst + 8) = *(uint4*)&tmp[8];
  }
}

// ---------------- causal GQA flash attention (v6) ---------------------------
// GQA head-pair sharing: one block = 2 heads of the same kvh group.
// Waves 0-1 -> head h0, waves 2-3 -> h1; each wave 32 q rows (2 M-frags).
// K/V staged ONCE per block feeds both heads -> LDS bytes per flop HALVED
// vs v5 (each kf/vf read feeds 2 MFMAs; total grid tiles halved at same
// per-tile LDS cost). Geometry stays balanced: 64-row q-tiles, mirror-paired
// jobs (qb=p, 63-p) = uniform 65 tiles/block; 256 blocks x 256 thr, 80KB LDS
// -> exactly 2 blocks/CU, all resident, tail-free.
// Static-max softmax (RMSNorm-bounded scores), Q pre-scaled by SCALE*log2e,
// XCD affinity: slot=bid&7 -> kvh=slot>>1 (2MB K+V per XCD L2).
__global__ __launch_bounds__(256, 2) void attn_fwd(const u16* __restrict__ Q,
                                                   const u16* __restrict__ K,
                                                   const u16* __restrict__ Vt,
                                                   u16* __restrict__ O) {
  const int bid  = blockIdx.x;
  const int slot = bid & 7, p = bid >> 3;          // p = mirror-pair 0..31
  const int kvh  = slot >> 1, hp = slot & 1;
  const int tid = threadIdx.x, wave = tid >> 6, lane = tid & 63;
  const int h  = kvh * 4 + hp * 2 + (wave >> 1);   // per-wave head
  const int wq = wave & 1;                         // row-half within q-tile
  __shared__ u16 Ks[2][64][128];                   // 32KB
  __shared__ u16 Vs[2][128][64];                   // 32KB
  __shared__ u16 Ps[4][32][64];                    // 16KB

  // block-level staging bases (pre-swizzled global source)
  const u16* gKb[4]; const u16* gVb[4];
  #pragma unroll
  for (int i = 0; i < 4; ++i) {
    int cc = wave * 4 + i;
    int rk = cc * 4 + (lane >> 4);
    gKb[i] = K + ((size_t)kvh * S_LEN + rk) * HDIM + ((lane & 15) ^ (rk & 7)) * 8;
    int rv = cc * 8 + (lane >> 3);
    gVb[i] = Vt + ((size_t)kvh * HDIM + rv) * S_LEN + ((lane & 7) ^ (rv & 7)) * 8;
  }
  auto stage = [&](int buf, int kvb) {
    #pragma unroll
    for (int i = 0; i < 4; ++i) {
      int cc = wave * 4 + i;
      gl2lds16(gKb[i] + (size_t)kvb * HDIM, &Ks[buf][cc * 4][0]);
      gl2lds16(gVb[i] + kvb,                &Vs[buf][cc * 8][0]);
    }
  };

  // swizzled LDS read offsets ((row&7) == (lane&7) for every fragment read)
  int offv[4];
  #pragma unroll
  for (int kk = 0; kk < 4; ++kk)
    offv[kk] = (kk * 64 + (lane >> 4) * 16) ^ ((lane & 7) << 4);
  const char* ksB = (const char*)Ks + (lane & 15) * 256;
  const char* vsB = (const char*)Vs + (lane & 15) * 128;
  const char* psB = (const char*)Ps + wave * 4096 + (lane & 15) * 128;
  char*       pwB = (char*)Ps + wave * 4096;
  const int   lx2 = (lane & 15) * 2;

  stage(0, 0);                                     // prologue: job0 tile0
  __syncthreads();
  int cur = 0;

  for (int job = 0; job < 2; ++job) {
    const int qb = job ? (63 - p) : p;
    const int ntiles = qb + 1;
    const int qg0 = qb * 64 + wq * 32 + (lane >> 4) * 4;  // + qm*16 + r = q row

    // Q fragments: 2 M-frags x 4 k-slices (per-wave head, per-wave row half)
    bf16x8 qf[2][4];
    #pragma unroll
    for (int qm = 0; qm < 2; ++qm) {
      const u16* qptr = Q + ((size_t)h * S_LEN + qb * 64 + wq * 32 + qm * 16 + (lane & 15)) * HDIM
                        + (lane >> 4) * 8;
      #pragma unroll
      for (int kk = 0; kk < 4; ++kk) qf[qm][kk] = *(const bf16x8*)(qptr + kk * 32);
    }

    float lsum[2][4];
    #pragma unroll
    for (int qm = 0; qm < 2; ++qm)
      #pragma unroll
      for (int r = 0; r < 4; ++r) lsum[qm][r] = 0.f;
    f32x4 o[2][8];
    #pragma unroll
    for (int qm = 0; qm < 2; ++qm)
      #pragma unroll
      for (int i = 0; i < 8; ++i) { f32x4 z = {0.f,0.f,0.f,0.f}; o[qm][i] = z; }

    for (int kt = 0; kt < ntiles; ++kt) {
      // ---- prefetch next tile (this job's kt+1, or job1's tile 0) ----
      if (kt + 1 < ntiles)      stage(cur ^ 1, (kt + 1) * 64);
      else if (job == 0)        stage(cur ^ 1, 0);

      const int bufo = cur << 14;                  // 16KB per K/V buffer half

      // ---- QK^T: each kf feeds both M-frags ----
      f32x4 sc[2][4];
      #pragma unroll
      for (int qm = 0; qm < 2; ++qm)
        #pragma unroll
        for (int i = 0; i < 4; ++i) { f32x4 z = {0.f,0.f,0.f,0.f}; sc[qm][i] = z; }
      __builtin_amdgcn_s_setprio(1);
      #pragma unroll
      for (int kk = 0; kk < 4; ++kk)
        #pragma unroll
        for (int nf = 0; nf < 4; ++nf) {
          bf16x8 kf = *(const bf16x8*)(ksB + bufo + nf * 4096 + offv[kk]);
          sc[0][nf] = mfma_bf16(qf[0][kk], kf, sc[0][nf]);
          sc[1][nf] = mfma_bf16(qf[1][kk], kf, sc[1][nf]);
        }
      __builtin_amdgcn_s_setprio(0);

      // ---- static-max softmax: e = 2^s directly; zero-mask on diag tile ----
      if (kt == ntiles - 1) {
        const int kvb = kt * 64;
        #pragma unroll
        for (int qm = 0; qm < 2; ++qm)
          #pragma unroll
          for (int nf = 0; nf < 4; ++nf) {
            int col = kvb + nf * 16 + (lane & 15);
            #pragma unroll
            for (int r = 0; r < 4; ++r) {
              float e = __builtin_amdgcn_exp2f(sc[qm][nf][r]);
              e = (col <= qg0 + qm * 16 + r) ? e : 0.f;
              sc[qm][nf][r] = e;
              lsum[qm][r] += e;
            }
          }
      } else {
        #pragma unroll
        for (int qm = 0; qm < 2; ++qm)
          #pragma unroll
          for (int nf = 0; nf < 4; ++nf)
            #pragma unroll
            for (int r = 0; r < 4; ++r) {
              float e = __builtin_amdgcn_exp2f(sc[qm][nf][r]);
              sc[qm][nf][r] = e;
              lsum[qm][r] += e;
            }
      }

      // ---- P write (swizzled; prow&7 unaffected by qm*16) ----
      #pragma unroll
      for (int qm = 0; qm < 2; ++qm)
        #pragma unroll
        for (int nf = 0; nf < 4; ++nf)
          #pragma unroll
          for (int r = 0; r < 4; ++r) {
            int prow = qm * 16 + (lane >> 4) * 4 + r;
            int bcol = (nf * 32 + lx2) ^ ((prow & 7) << 4);
            *(u16*)(pwB + prow * 128 + bcol) = f2bf_fast(sc[qm][nf][r]);
          }

      // ---- PV: each vf feeds both M-frags ----
      __builtin_amdgcn_s_setprio(1);
      #pragma unroll
      for (int ks = 0; ks < 2; ++ks) {
        bf16x8 pf0 = *(const bf16x8*)(psB + offv[ks]);
        bf16x8 pf1 = *(const bf16x8*)(psB + 2048 + offv[ks]);
        #pragma unroll
        for (int nf2 = 0; nf2 < 8; ++nf2) {
          bf16x8 vf = *(const bf16x8*)(vsB + bufo + nf2 * 2048 + offv[ks]);
          o[0][nf2] = mfma_bf16(pf0, vf, o[0][nf2]);
          o[1][nf2] = mfma_bf16(pf1, vf, o[1][nf2]);
        }
      }
      __builtin_amdgcn_s_setprio(0);

      __syncthreads();                             // staged buf ready, cur reusable
      cur ^= 1;
    }

    // ---- epilogue: reduce lane-local lsum across the 16-lane row group ----
    #pragma unroll
    for (int qm = 0; qm < 2; ++qm)
      #pragma unroll
      for (int r = 0; r < 4; ++r) {
        float lt = lsum[qm][r];
        #pragma unroll
        for (int m = 1; m < 16; m <<= 1) lt += __shfl_xor(lt, m);
        float inv = 1.f / lt;
        int srow = qg0 + qm * 16 + r;
        #pragma unroll
        for (int nf2 = 0; nf2 < 8; ++nf2) {
          int col = h * HDIM + nf2 * 16 + (lane & 15);
          O[(size_t)srow * HIDN + col] = f2bf_fast(o[qm][nf2][r] * inv);
        }
      }
  }
}

// ---------------- launch -----------------------------------------------------
extern "C" void kernel_launch(void* const* d_in, const int* in_sizes, int n_in,
                              void* d_out, int out_size, void* d_ws, size_t ws_size,
                              hipStream_t stream) {
  (void)in_sizes; (void)n_in; (void)out_size; (void)ws_size;
  const float* h    = (const float*)d_in[0];
  const float* cosb = (const float*)d_in[1];
  const float* sinb = (const float*)d_in[2];
  const float* Wq   = (const float*)d_in[3];
  const float* Wk   = (const float*)d_in[4];
  const float* Wv   = (const float*)d_in[5];
  const float* Wo   = (const float*)d_in[6];
  const float* qw   = (const float*)d_in[7];
  const float* kw   = (const float*)d_in[8];
  float* out = (float*)d_out;

  char* ws = (char*)d_ws;
  u16* hbf  = (u16*)(ws);
  u16* Kb   = (u16*)(ws + (16u << 20));
  u16* Vtb  = (u16*)(ws + (20u << 20));
  u16* wqkv = (u16*)(ws + (24u << 20));
  u16* Qb   = (u16*)(ws + (24u << 20));
  u16* qkvb = (u16*)(ws + (40u << 20));
  u16* wob  = (u16*)(ws + (40u << 20));

  cvt_f32_bf16<<<4096, 256, 0, stream>>>(h, hbf);
  cvt_f32_bf16<<<2048, 256, 0, stream>>>(Wq, wqkv);
  cvt_f32_bf16<<<512, 256, 0, stream>>>(Wk, wqkv + 4u * 1024 * 1024);
  cvt_f32_bf16<<<512, 256, 0, stream>>>(Wv, wqkv + 5u * 1024 * 1024);

  gemm_big<192, 3, true><<<dim3(16, 16), 512, 0, stream>>>(hbf, wqkv, qkvb,
                                                           4096, 3072, 2048);

  norm_rope<<<4096, 256, 0, stream>>>(qkvb, cosb, sinb, qw, kw, Qb, Kb);
  vtrans<<<dim3(64, 2, 4), 256, 0, stream>>>(qkvb, Vtb);

  cvt_f32_bf16<<<2048, 256, 0, stream>>>(Wo, wob);

  attn_fwd<<<dim3(256), 256, 0, stream>>>(Qb, Kb, Vtb, hbf);

  gemm_big<128, 2, false><<<dim3(16, 16), 512, 0, stream>>>(hbf, wob, out,
                                                            4096, 2048, 2048);
}

// Round 12
// 240.698 us; speedup vs baseline: 1.1097x; 1.1089x over previous
//
#include <hip/hip_runtime.h>

typedef unsigned short u16;
typedef unsigned int   u32;
typedef __bf16 bf16x8 __attribute__((ext_vector_type(8)));
typedef float  f32x4  __attribute__((ext_vector_type(4)));

#define S_LEN 4096
#define HIDN  2048
#define NHEAD 16
#define NKVH  4
#define HDIM  128
#define ROTD  64
#define QKVN  3072

__device__ __forceinline__ u16 f2bf(float f) {
  union { float f; u32 u; } v; v.f = f;
  u32 r = v.u + 0x7FFFu + ((v.u >> 16) & 1u);   // RNE
  return (u16)(r >> 16);
}
__device__ __forceinline__ u16 f2bf_fast(float f) {
  union { __bf16 b; u16 u; } cv; cv.b = (__bf16)f; return cv.u;   // v_cvt hw RNE
}
__device__ __forceinline__ float bf2f(u16 u) {
  union { u32 u; float f; } v; v.u = ((u32)u) << 16; return v.f;
}
__device__ __forceinline__ void gl2lds16(const u16* g, u16* l) {
  __builtin_amdgcn_global_load_lds((const __attribute__((address_space(1))) void*)g,
                                   (__attribute__((address_space(3))) void*)l, 16, 0, 0);
}
__device__ __forceinline__ f32x4 mfma_bf16(bf16x8 a, bf16x8 b, f32x4 c) {
  return __builtin_amdgcn_mfma_f32_16x16x32_bf16(a, b, c, 0, 0, 0);
}
template <int N> __device__ __forceinline__ void vmwait() {
  if constexpr (N == 7)      asm volatile("s_waitcnt vmcnt(7)" ::: "memory");
  else if constexpr (N == 6) asm volatile("s_waitcnt vmcnt(6)" ::: "memory");
  else                       asm volatile("s_waitcnt vmcnt(0)" ::: "memory");
}

// ---------------- f32 -> bf16 convert (8 elems/thread, exact grid) ----------
__global__ __launch_bounds__(256) void cvt_f32_bf16(const float* __restrict__ in,
                                                    u16* __restrict__ out) {
  size_t i = ((size_t)blockIdx.x * 256 + threadIdx.x) * 8;
  float4 a = *(const float4*)(in + i);
  float4 b = *(const float4*)(in + i + 4);
  uint4 r;
  r.x = (u32)f2bf(a.x) | ((u32)f2bf(a.y) << 16);
  r.y = (u32)f2bf(a.z) | ((u32)f2bf(a.w) << 16);
  r.z = (u32)f2bf(b.x) | ((u32)f2bf(b.y) << 16);
  r.w = (u32)f2bf(b.z) | ((u32)f2bf(b.w) << 16);
  *(uint4*)(out + i) = r;
}

// ---------------- GEMM v2: C[M,N] = A[M,K]*B[N,K]^T (unchanged from R9) -----
template <int BN, int NB, bool BF16OUT>
__global__ __launch_bounds__(512, 2) void gemm_big(const u16* __restrict__ A,
                                                   const u16* __restrict__ Bm,
                                                   void* __restrict__ Cp,
                                                   int M, int N, int K) {
  constexpr int WNC = BN / 4;
  constexpr int NF  = WNC / 16;
  constexpr int ASZ = 256 * 128;
  constexpr int BUF = ASZ + BN * 128;
  constexpr int LOADS = 4 + NB;
  __shared__ __align__(1024) char lds[2 * BUF];

  const int tid = threadIdx.x, wave = tid >> 6, lane = tid & 63;
  const int wm = wave >> 2, wn = wave & 3;
  const int row0 = blockIdx.x * 256, col0 = blockIdx.y * BN;
  const int l8 = lane >> 3, l7 = lane & 7;
  const int T = K >> 6;

  const u16* gA[4]; const u16* gB[NB];
  u16* ldsA[4]; u16* ldsB[NB];
  #pragma unroll
  for (int i = 0; i < 4; ++i) {
    gA[i]  = A + (size_t)(row0 + wave * 32 + i * 8 + l8) * K + (l7 ^ l8) * 8;
    ldsA[i] = (u16*)(lds + wave * 4096 + i * 1024);
  }
  #pragma unroll
  for (int i = 0; i < NB; ++i) {
    gB[i]  = Bm + (size_t)(col0 + wave * (BN / 8) + i * 8 + l8) * K + (l7 ^ l8) * 8;
    ldsB[i] = (u16*)(lds + ASZ + wave * (BN * 16) + i * 1024);
  }
  auto stage = [&](int buf, int t) {
    const size_t ko = (size_t)t * 64;
    #pragma unroll
    for (int i = 0; i < 4; ++i)
      gl2lds16(gA[i] + ko, (u16*)((char*)ldsA[i] + buf * BUF));
    #pragma unroll
    for (int i = 0; i < NB; ++i)
      gl2lds16(gB[i] + ko, (u16*)((char*)ldsB[i] + buf * BUF));
  };

  const int colx0 = (((lane >> 4))     ^ l7) * 16;
  const int colx1 = ((4 + (lane >> 4)) ^ l7) * 16;
  const char* aB = lds + (wm * 128 + (lane & 15)) * 128;
  const char* bB = lds + ASZ + (wn * WNC + (lane & 15)) * 128;

  f32x4 acc[8][NF];
  #pragma unroll
  for (int i = 0; i < 8; ++i)
    #pragma unroll
    for (int j = 0; j < NF; ++j) { f32x4 z = {0.f,0.f,0.f,0.f}; acc[i][j] = z; }

  stage(0, 0);
  stage(1, 1);
  vmwait<LOADS>();
  __builtin_amdgcn_s_barrier();

  for (int t = 0; t < T; ++t) {
    const int bo = (t & 1) * BUF;
    #pragma unroll
    for (int kh = 0; kh < 2; ++kh) {
      const int cx = kh ? colx1 : colx0;
      bf16x8 bfr[NF];
      #pragma unroll
      for (int nf = 0; nf < NF; ++nf)
        bfr[nf] = *(const bf16x8*)(bB + bo + nf * 2048 + cx);
      #pragma unroll
      for (int mh = 0; mh < 2; ++mh) {
        bf16x8 af[4];
        #pragma unroll
        for (int mf = 0; mf < 4; ++mf)
          af[mf] = *(const bf16x8*)(aB + bo + mh * 8192 + mf * 2048 + cx);
        __builtin_amdgcn_s_setprio(1);
        #pragma unroll
        for (int mf = 0; mf < 4; ++mf)
          #pragma unroll
          for (int nf = 0; nf < NF; ++nf)
            acc[mh * 4 + mf][nf] = mfma_bf16(af[mf], bfr[nf], acc[mh * 4 + mf][nf]);
        __builtin_amdgcn_s_setprio(0);
      }
    }
    asm volatile("s_waitcnt lgkmcnt(0)" ::: "memory");
    __builtin_amdgcn_s_barrier();
    if (t + 2 < T) stage(t & 1, t + 2);
    if (t + 1 < T) {
      if (t + 2 < T) vmwait<LOADS>();
      else           vmwait<0>();
      __builtin_amdgcn_s_barrier();
    }
  }

  const int mwv = row0 + wm * 128, nwv = col0 + wn * WNC;
  #pragma unroll
  for (int mf8 = 0; mf8 < 8; ++mf8)
    #pragma unroll
    for (int nf = 0; nf < NF; ++nf)
      #pragma unroll
      for (int r = 0; r < 4; ++r) {
        int m = mwv + (mf8 >> 2) * 64 + (mf8 & 3) * 16 + (lane >> 4) * 4 + r;
        int n = nwv + nf * 16 + (lane & 15);
        float v = acc[mf8][nf][r];
        if (BF16OUT) ((u16*)Cp)[(size_t)m * N + n] = f2bf(v);
        else         ((float*)Cp)[(size_t)m * N + n] = v;
      }
}

// ---------------- fused RMSNorm (full row) + partial RoPE + head transpose --
__global__ __launch_bounds__(256) void norm_rope(const u16* __restrict__ qkv,
                                                 const float* __restrict__ cosb,
                                                 const float* __restrict__ sinb,
                                                 const float* __restrict__ qw,
                                                 const float* __restrict__ kw,
                                                 u16* __restrict__ Qo,
                                                 u16* __restrict__ Ko) {
  const int s = blockIdx.x, t = threadIdx.x;
  const int wave = t >> 6, lane = t & 63;
  const float SL = 0.08838834764831845f * 1.4426950408889634f;  // SCALE*log2e
  __shared__ float rowbuf[HIDN];
  __shared__ float red[4];
  const u16* base = qkv + (size_t)s * QKVN;

  float x[8];
  {
    uint4 v = *(const uint4*)(base + t * 8);
    u32 w4[4] = {v.x, v.y, v.z, v.w};
    #pragma unroll
    for (int j = 0; j < 4; ++j) {
      x[2*j]   = bf2f((u16)(w4[j] & 0xffffu));
      x[2*j+1] = bf2f((u16)(w4[j] >> 16));
    }
  }
  float ss = 0.f;
  #pragma unroll
  for (int j = 0; j < 8; ++j) ss += x[j] * x[j];
  #pragma unroll
  for (int m = 1; m < 64; m <<= 1) ss += __shfl_xor(ss, m);
  if (lane == 0) red[wave] = ss;
  __syncthreads();
  float rs = rsqrtf((red[0]+red[1]+red[2]+red[3]) * (1.0f / HIDN) + 1e-6f);
  #pragma unroll
  for (int j = 0; j < 8; ++j) rowbuf[t*8 + j] = x[j] * rs * qw[t*8 + j];
  __syncthreads();
  {
    int i0 = t * 8, d0 = i0 & (HDIM - 1), hh = i0 >> 7;
    float o[8];
    if (d0 < ROTD) {
      #pragma unroll
      for (int j = 0; j < 8; ++j) {
        int d = d0 + j;
        float rot = (d < 32) ? -rowbuf[i0 + j + 32] : rowbuf[i0 + j - 32];
        o[j] = rowbuf[i0 + j] * cosb[s*ROTD + d] + rot * sinb[s*ROTD + d];
      }
    } else {
      #pragma unroll
      for (int j = 0; j < 8; ++j) o[j] = rowbuf[i0 + j];
    }
    uint4 r;
    r.x = (u32)f2bf(o[0]*SL) | ((u32)f2bf(o[1]*SL) << 16);
    r.y = (u32)f2bf(o[2]*SL) | ((u32)f2bf(o[3]*SL) << 16);
    r.z = (u32)f2bf(o[4]*SL) | ((u32)f2bf(o[5]*SL) << 16);
    r.w = (u32)f2bf(o[6]*SL) | ((u32)f2bf(o[7]*SL) << 16);
    *(uint4*)(Qo + ((size_t)hh * S_LEN + s) * HDIM + d0) = r;
  }

  const u16* kbase = base + HIDN;
  float y0, y1;
  { u32 v = *(const u32*)(kbase + t * 2); y0 = bf2f((u16)(v & 0xffffu)); y1 = bf2f((u16)(v >> 16)); }
  float ss2 = y0*y0 + y1*y1;
  #pragma unroll
  for (int m = 1; m < 64; m <<= 1) ss2 += __shfl_xor(ss2, m);
  __syncthreads();
  if (lane == 0) red[wave] = ss2;
  __syncthreads();
  float rs2 = rsqrtf((red[0]+red[1]+red[2]+red[3]) * (1.0f / 512.0f) + 1e-6f);
  rowbuf[t*2]     = y0 * rs2 * kw[t*2];
  rowbuf[t*2 + 1] = y1 * rs2 * kw[t*2 + 1];
  __syncthreads();
  {
    int i0 = t * 2, d0 = i0 & (HDIM - 1), hh = i0 >> 7;
    float o0, o1;
    if (d0 < ROTD) {
      float r0 = (d0 < 32) ? -rowbuf[i0 + 32] : rowbuf[i0 - 32];
      float r1 = (d0 + 1 < 32) ? -rowbuf[i0 + 1 + 32] : rowbuf[i0 + 1 - 32];
      o0 = rowbuf[i0]     * cosb[s*ROTD + d0]     + r0 * sinb[s*ROTD + d0];
      o1 = rowbuf[i0 + 1] * cosb[s*ROTD + d0 + 1] + r1 * sinb[s*ROTD + d0 + 1];
    } else { o0 = rowbuf[i0]; o1 = rowbuf[i0 + 1]; }
    u32 r = (u32)f2bf(o0) | ((u32)f2bf(o1) << 16);
    *(u32*)(Ko + ((size_t)hh * S_LEN + s) * HDIM + d0) = r;
  }
}

// ---------------- V transpose: qkv[S][3072] v-cols -> Vt[NKV][HD][S] --------
__global__ __launch_bounds__(256) void vtrans(const u16* __restrict__ qkv,
                                              u16* __restrict__ Vt) {
  const int sb = blockIdx.x * 64, db = blockIdx.y * 64, kvh = blockIdx.z;
  __shared__ u16 tile[64][72];
  const int t = threadIdx.x;
  {
    int r = t >> 2, cc = (t & 3) * 16;
    const u16* src = qkv + (size_t)(sb + r) * QKVN + 2560 + kvh * HDIM + db + cc;
    *(uint4*)&tile[r][cc]     = *(const uint4*)(src);
    *(uint4*)&tile[r][cc + 8] = *(const uint4*)(src + 8);
  }
  __syncthreads();
  {
    int d = t >> 2, sc = (t & 3) * 16;
    u16 tmp[16];
    #pragma unroll
    for (int j = 0; j < 16; ++j) tmp[j] = tile[sc + j][d];
    u16* dst = Vt + ((size_t)kvh * HDIM + db + d) * S_LEN + sb + sc;
    *(uint4*)dst       = *(uint4*)&tmp[0];
    *(uint4*)(dst + 8) = *(uint4*)&tmp[8];
  }
}

// ---------------- causal GQA flash attention (v7: quadrant waves) -----------
// v5 shell (512 blocks flat, XCD decode, mirror-paired jobs qb=p/63-p, 65
// tiles uniform, dbuf K/V, 72KB, 2 blocks/CU) with QUADRANT wave split:
// wave (rh, kvh2) owns q-rows [rh*32, rh*32+32) x kv [kvh2*32, kvh2*32+32)
// of each 64x64 tile. Each wave holds 2 M-frags -> every kf/vf ds_read
// feeds 2 MFMAs: 18 reads per 32 MFMAs (v5: 34) -> LDS read traffic ~halved.
// All 4 waves compute every tile (no duty-cycle hole); P stays wave-private.
// o/lsum are kv-half partials -> one cross-wave LDS add per job (exactly
// additive thanks to static-max softmax: no running max, no rescale).
// Diagonal tile: quadrant (rh=0, kvh2=1) is entirely causal-masked -> skip.
__global__ __launch_bounds__(256, 2) void attn_fwd(const u16* __restrict__ Q,
                                                   const u16* __restrict__ K,
                                                   const u16* __restrict__ Vt,
                                                   u16* __restrict__ O) {
  const int n    = blockIdx.x;
  const int slot = n & 7, kq = n >> 3;             // kq 0..63
  const int kvh  = slot >> 1;                      // XCD affinity: 2 slots/kvh
  const int h    = kvh * 4 + (slot & 1) * 2 + (kq & 1);
  const int p    = kq >> 1;                        // mirror-pair index 0..31
  const int tid = threadIdx.x, wave = tid >> 6, lane = tid & 63;
  const int rh   = wave & 1;                       // row-half of the q tile
  const int kvh2 = wave >> 1;                      // kv-half of the kv tile
  __shared__ u16 Ks[2][64][128];                   // 32KB
  __shared__ u16 Vs[2][128][64];                   // 32KB
  __shared__ u16 Ps[2][32][64];                    //  8KB (per row-half)

  // staging (identical to v5): 16 K chunks + 16 V chunks, 4+4 per wave
  const u16* gKb[4]; const u16* gVb[4];
  #pragma unroll
  for (int i = 0; i < 4; ++i) {
    int cc = wave * 4 + i;
    int rk = cc * 4 + (lane >> 4);
    gKb[i] = K + ((size_t)kvh * S_LEN + rk) * HDIM + ((lane & 15) ^ (rk & 7)) * 8;
    int rv = cc * 8 + (lane >> 3);
    gVb[i] = Vt + ((size_t)kvh * HDIM + rv) * S_LEN + ((lane & 7) ^ (rv & 7)) * 8;
  }
  auto stage = [&](int buf, int kvb) {
    #pragma unroll
    for (int i = 0; i < 4; ++i) {
      int cc = wave * 4 + i;
      gl2lds16(gKb[i] + (size_t)kvb * HDIM, &Ks[buf][cc * 4][0]);
      gl2lds16(gVb[i] + kvb,                &Vs[buf][cc * 8][0]);
    }
  };

  // swizzled LDS read offsets ((row&7) == (lane&7) for every fragment read)
  int offv[4];
  #pragma unroll
  for (int kk = 0; kk < 4; ++kk)
    offv[kk] = (kk * 64 + (lane >> 4) * 16) ^ ((lane & 7) << 4);
  const char* ksB = (const char*)Ks + kvh2 * 8192 + (lane & 15) * 256;
  const char* vsB = (const char*)Vs + (lane & 15) * 128;
  const char* psB = (const char*)Ps + rh * 4096 + (lane & 15) * 128;
  char*       pwB = (char*)Ps + rh * 4096;
  const int   lx2 = (lane & 15) * 2;
  const int   vko = offv[kvh2];                    // vf/pf col offset (kv half)

  stage(0, 0);                                     // prologue: job0 tile0
  __syncthreads();
  int cur = 0;

  for (int job = 0; job < 2; ++job) {
    const int qb = job ? (63 - p) : p;
    const int ntiles = qb + 1;
    const int qg0 = qb * 64 + rh * 32 + (lane >> 4) * 4;  // + qm*16 + r = q row

    // Q fragments: 2 M-frags (rows rh*32 + qm*16 + (lane&15)) x 4 k-slices
    bf16x8 qf[2][4];
    #pragma unroll
    for (int qm = 0; qm < 2; ++qm) {
      const u16* qptr = Q + ((size_t)h * S_LEN + qb * 64 + rh * 32 + qm * 16 + (lane & 15)) * HDIM
                        + (lane >> 4) * 8;
      #pragma unroll
      for (int kk = 0; kk < 4; ++kk) qf[qm][kk] = *(const bf16x8*)(qptr + kk * 32);
    }

    float lsum[2][4];
    #pragma unroll
    for (int qm = 0; qm < 2; ++qm)
      #pragma unroll
      for (int r = 0; r < 4; ++r) lsum[qm][r] = 0.f;
    f32x4 o[2][8];
    #pragma unroll
    for (int qm = 0; qm < 2; ++qm)
      #pragma unroll
      for (int i = 0; i < 8; ++i) { f32x4 z = {0.f,0.f,0.f,0.f}; o[qm][i] = z; }

    for (int kt = 0; kt < ntiles; ++kt) {
      // ---- prefetch next tile (this job's kt+1, or job1's tile 0) ----
      if (kt + 1 < ntiles)      stage(cur ^ 1, (kt + 1) * 64);
      else if (job == 0)        stage(cur ^ 1, 0);

      const int bufo = cur << 14;                  // 16KB per K/V buffer half
      const bool diag = (kt == ntiles - 1);

      // quadrant (rh=0, kvh2=1) on the diagonal tile is fully masked -> skip
      if (!(diag && kvh2 == 1 && rh == 0)) {
        // ---- QK^T: 8 kf reads feed 16 MFMAs (2 M-frags each) ----
        f32x4 sc[2][2];
        #pragma unroll
        for (int qm = 0; qm < 2; ++qm)
          #pragma unroll
          for (int i = 0; i < 2; ++i) { f32x4 z = {0.f,0.f,0.f,0.f}; sc[qm][i] = z; }
        __builtin_amdgcn_s_setprio(1);
        #pragma unroll
        for (int kk = 0; kk < 4; ++kk)
          #pragma unroll
          for (int nf = 0; nf < 2; ++nf) {
            bf16x8 kf = *(const bf16x8*)(ksB + bufo + nf * 4096 + offv[kk]);
            sc[0][nf] = mfma_bf16(qf[0][kk], kf, sc[0][nf]);
            sc[1][nf] = mfma_bf16(qf[1][kk], kf, sc[1][nf]);
          }
        __builtin_amdgcn_s_setprio(0);

        // ---- static-max softmax: e = 2^s; zero-mask on diagonal tile ----
        if (diag) {
          const int kvb = kt * 64;
          #pragma unroll
          for (int qm = 0; qm < 2; ++qm)
            #pragma unroll
            for (int nf = 0; nf < 2; ++nf) {
              int col = kvb + kvh2 * 32 + nf * 16 + (lane & 15);
              #pragma unroll
              for (int r = 0; r < 4; ++r) {
                float e = __builtin_amdgcn_exp2f(sc[qm][nf][r]);
                e = (col <= qg0 + qm * 16 + r) ? e : 0.f;
                sc[qm][nf][r] = e;
                lsum[qm][r] += e;
              }
            }
        } else {
          #pragma unroll
          for (int qm = 0; qm < 2; ++qm)
            #pragma unroll
            for (int nf = 0; nf < 2; ++nf)
              #pragma unroll
              for (int r = 0; r < 4; ++r) {
                float e = __builtin_amdgcn_exp2f(sc[qm][nf][r]);
                sc[qm][nf][r] = e;
                lsum[qm][r] += e;
              }
        }

        // ---- P write (wave-private quadrant, swizzled) ----
        #pragma unroll
        for (int qm = 0; qm < 2; ++qm)
          #pragma unroll
          for (int nf = 0; nf < 2; ++nf)
            #pragma unroll
            for (int r = 0; r < 4; ++r) {
              int prow = qm * 16 + (lane >> 4) * 4 + r;
              int bcol = (kvh2 * 64 + nf * 32 + lx2) ^ ((prow & 7) << 4);
              *(u16*)(pwB + prow * 128 + bcol) = f2bf_fast(sc[qm][nf][r]);
            }

        // ---- PV: 8 vf reads feed 16 MFMAs (2 M-frags each) ----
        bf16x8 pf0, pf1;
        pf0 = *(const bf16x8*)(psB + vko);
        pf1 = *(const bf16x8*)(psB + 2048 + vko);
        __builtin_amdgcn_s_setprio(1);
        #pragma unroll
        for (int nf2 = 0; nf2 < 8; ++nf2) {
          bf16x8 vf = *(const bf16x8*)(vsB + bufo + nf2 * 2048 + vko);
          o[0][nf2] = mfma_bf16(pf0, vf, o[0][nf2]);
          o[1][nf2] = mfma_bf16(pf1, vf, o[1][nf2]);
        }
        __builtin_amdgcn_s_setprio(0);
      }

      __syncthreads();                             // staged buf ready, cur reusable
      cur ^= 1;
    }

    // ---- cross-kv-half combine (partials are exactly additive) ----
    // free scratch: K/V buffer half cur^1 (just consumed); Ps is idle.
    {
      f32x4* scr = (f32x4*)((rh == 0) ? (char*)Ks + (cur ^ 1) * 16384
                                      : (char*)Vs + (cur ^ 1) * 16384);
      float* lsc = (float*)Ps;
      if (kvh2 == 1) {
        #pragma unroll
        for (int qm = 0; qm < 2; ++qm)
          #pragma unroll
          for (int nf2 = 0; nf2 < 8; ++nf2)
            scr[(qm * 8 + nf2) * 64 + lane] = o[qm][nf2];
        #pragma unroll
        for (int qm = 0; qm < 2; ++qm)
          #pragma unroll
          for (int r = 0; r < 4; ++r)
            lsc[rh * 512 + (qm * 4 + r) * 64 + lane] = lsum[qm][r];
      }
      __syncthreads();
      if (kvh2 == 0) {
        #pragma unroll
        for (int qm = 0; qm < 2; ++qm)
          #pragma unroll
          for (int nf2 = 0; nf2 < 8; ++nf2)
            o[qm][nf2] += scr[(qm * 8 + nf2) * 64 + lane];
        #pragma unroll
        for (int qm = 0; qm < 2; ++qm)
          #pragma unroll
          for (int r = 0; r < 4; ++r)
            lsum[qm][r] += lsc[rh * 512 + (qm * 4 + r) * 64 + lane];

        // ---- epilogue (waves 0,1 cover all 64 rows) ----
        #pragma unroll
        for (int qm = 0; qm < 2; ++qm)
          #pragma unroll
          for (int r = 0; r < 4; ++r) {
            float lt = lsum[qm][r];
            #pragma unroll
            for (int m = 1; m < 16; m <<= 1) lt += __shfl_xor(lt, m);
            float inv = 1.f / lt;
            int srow = qg0 + qm * 16 + r;
            #pragma unroll
            for (int nf2 = 0; nf2 < 8; ++nf2) {
              int col = h * HDIM + nf2 * 16 + (lane & 15);
              O[(size_t)srow * HIDN + col] = f2bf_fast(o[qm][nf2][r] * inv);
            }
          }
      }
      __syncthreads();                             // scratch safe before job1 staging
    }
  }
}

// ---------------- launch -----------------------------------------------------
extern "C" void kernel_launch(void* const* d_in, const int* in_sizes, int n_in,
                              void* d_out, int out_size, void* d_ws, size_t ws_size,
                              hipStream_t stream) {
  (void)in_sizes; (void)n_in; (void)out_size; (void)ws_size;
  const float* h    = (const float*)d_in[0];
  const float* cosb = (const float*)d_in[1];
  const float* sinb = (const float*)d_in[2];
  const float* Wq   = (const float*)d_in[3];
  const float* Wk   = (const float*)d_in[4];
  const float* Wv   = (const float*)d_in[5];
  const float* Wo   = (const float*)d_in[6];
  const float* qw   = (const float*)d_in[7];
  const float* kw   = (const float*)d_in[8];
  float* out = (float*)d_out;

  char* ws = (char*)d_ws;
  u16* hbf  = (u16*)(ws);
  u16* Kb   = (u16*)(ws + (16u << 20));
  u16* Vtb  = (u16*)(ws + (20u << 20));
  u16* wqkv = (u16*)(ws + (24u << 20));
  u16* Qb   = (u16*)(ws + (24u << 20));
  u16* qkvb = (u16*)(ws + (40u << 20));
  u16* wob  = (u16*)(ws + (40u << 20));

  cvt_f32_bf16<<<4096, 256, 0, stream>>>(h, hbf);
  cvt_f32_bf16<<<2048, 256, 0, stream>>>(Wq, wqkv);
  cvt_f32_bf16<<<512, 256, 0, stream>>>(Wk, wqkv + 4u * 1024 * 1024);
  cvt_f32_bf16<<<512, 256, 0, stream>>>(Wv, wqkv + 5u * 1024 * 1024);

  gemm_big<192, 3, true><<<dim3(16, 16), 512, 0, stream>>>(hbf, wqkv, qkvb,
                                                           4096, 3072, 2048);

  norm_rope<<<4096, 256, 0, stream>>>(qkvb, cosb, sinb, qw, kw, Qb, Kb);
  vtrans<<<dim3(64, 2, 4), 256, 0, stream>>>(qkvb, Vtb);

  cvt_f32_bf16<<<2048, 256, 0, stream>>>(Wo, wob);

  attn_fwd<<<dim3(512), 256, 0, stream>>>(Qb, Kb, Vtb, hbf);

  gemm_big<128, 2, false><<<dim3(16, 16), 512, 0, stream>>>(hbf, wob, out,
                                                            4096, 2048, 2048);
}

// Round 13
// 240.469 us; speedup vs baseline: 1.1107x; 1.0010x over previous
//
#include <hip/hip_runtime.h>

typedef unsigned short u16;
typedef unsigned int   u32;
typedef __bf16 bf16x8 __attribute__((ext_vector_type(8)));
typedef float  f32x4  __attribute__((ext_vector_type(4)));

#define S_LEN 4096
#define HIDN  2048
#define NHEAD 16
#define NKVH  4
#define HDIM  128
#define ROTD  64
#define QKVN  3072

__device__ __forceinline__ u16 f2bf(float f) {
  union { float f; u32 u; } v; v.f = f;
  u32 r = v.u + 0x7FFFu + ((v.u >> 16) & 1u);   // RNE
  return (u16)(r >> 16);
}
__device__ __forceinline__ u16 f2bf_fast(float f) {
  union { __bf16 b; u16 u; } cv; cv.b = (__bf16)f; return cv.u;   // v_cvt hw RNE
}
__device__ __forceinline__ float bf2f(u16 u) {
  union { u32 u; float f; } v; v.u = ((u32)u) << 16; return v.f;
}
__device__ __forceinline__ void gl2lds16(const u16* g, u16* l) {
  __builtin_amdgcn_global_load_lds((const __attribute__((address_space(1))) void*)g,
                                   (__attribute__((address_space(3))) void*)l, 16, 0, 0);
}
__device__ __forceinline__ f32x4 mfma_bf16(bf16x8 a, bf16x8 b, f32x4 c) {
  return __builtin_amdgcn_mfma_f32_16x16x32_bf16(a, b, c, 0, 0, 0);
}
template <int N> __device__ __forceinline__ void vmwait() {
  if constexpr (N == 7)      asm volatile("s_waitcnt vmcnt(7)" ::: "memory");
  else if constexpr (N == 6) asm volatile("s_waitcnt vmcnt(6)" ::: "memory");
  else                       asm volatile("s_waitcnt vmcnt(0)" ::: "memory");
}

// ---------------- fused f32 -> bf16 convert: h | Wq | Wk | Wv (one launch) --
__global__ __launch_bounds__(256) void cvt4_f32_bf16(const float* __restrict__ h,
                                                     const float* __restrict__ Wq,
                                                     const float* __restrict__ Wk,
                                                     const float* __restrict__ Wv,
                                                     u16* __restrict__ hbf,
                                                     u16* __restrict__ wqkv) {
  const int b = blockIdx.x;
  const float* src; u16* dst;
  if (b < 4096)      { src = h  + (size_t)b * 2048;           dst = hbf  + (size_t)b * 2048; }
  else if (b < 6144) { src = Wq + (size_t)(b - 4096) * 2048;  dst = wqkv + (size_t)(b - 4096) * 2048; }
  else if (b < 6656) { src = Wk + (size_t)(b - 6144) * 2048;  dst = wqkv + 4194304u + (size_t)(b - 6144) * 2048; }
  else               { src = Wv + (size_t)(b - 6656) * 2048;  dst = wqkv + 5242880u + (size_t)(b - 6656) * 2048; }
  size_t i = (size_t)threadIdx.x * 8;
  float4 a = *(const float4*)(src + i);
  float4 c = *(const float4*)(src + i + 4);
  uint4 r;
  r.x = (u32)f2bf(a.x) | ((u32)f2bf(a.y) << 16);
  r.y = (u32)f2bf(a.z) | ((u32)f2bf(a.w) << 16);
  r.z = (u32)f2bf(c.x) | ((u32)f2bf(c.y) << 16);
  r.w = (u32)f2bf(c.z) | ((u32)f2bf(c.w) << 16);
  *(uint4*)(dst + i) = r;
}

// ---------------- plain f32 -> bf16 convert (Wo, after qkvb is dead) --------
__global__ __launch_bounds__(256) void cvt_f32_bf16(const float* __restrict__ in,
                                                    u16* __restrict__ out) {
  size_t i = ((size_t)blockIdx.x * 256 + threadIdx.x) * 8;
  float4 a = *(const float4*)(in + i);
  float4 b = *(const float4*)(in + i + 4);
  uint4 r;
  r.x = (u32)f2bf(a.x) | ((u32)f2bf(a.y) << 16);
  r.y = (u32)f2bf(a.z) | ((u32)f2bf(a.w) << 16);
  r.z = (u32)f2bf(b.x) | ((u32)f2bf(b.y) << 16);
  r.w = (u32)f2bf(b.z) | ((u32)f2bf(b.w) << 16);
  *(uint4*)(out + i) = r;
}

// ---------------- GEMM v3: C[M,N] = A[M,K]*B[N,K]^T, 8-phase schedule -------
// BM=256 x BN (192/128), BK=64, 8 waves (2M x 4N), per-wave 128 x BN/4.
// Double-buffered LDS, 2-tile lookahead, counted vmcnt(LOADS) once per tile.
// NEW (R13): per K-tile 4 sub-phases (kh x mh), each the m201 barrier-pair:
//   {ds_read subtile -> s_barrier -> lgkmcnt(0) -> setprio(1) -> MFMA ->
//    setprio(0) -> s_barrier}
// Raw s_barrier (no waitcnt drain) lets each wave's reads stay in flight
// across the barrier; phase alternation saturates LDS pipe and matrix pipe
// in turn (T3; unlocks T2 swizzle + T5 setprio per the regime gate).
template <int BN, int NB, bool BF16OUT>
__global__ __launch_bounds__(512, 2) void gemm_big(const u16* __restrict__ A,
                                                   const u16* __restrict__ Bm,
                                                   void* __restrict__ Cp,
                                                   int M, int N, int K) {
  constexpr int WNC = BN / 4;
  constexpr int NF  = WNC / 16;
  constexpr int ASZ = 256 * 128;
  constexpr int BUF = ASZ + BN * 128;
  constexpr int LOADS = 4 + NB;
  __shared__ __align__(1024) char lds[2 * BUF];

  const int tid = threadIdx.x, wave = tid >> 6, lane = tid & 63;
  const int wm = wave >> 2, wn = wave & 3;
  const int row0 = blockIdx.x * 256, col0 = blockIdx.y * BN;
  const int l8 = lane >> 3, l7 = lane & 7;
  const int T = K >> 6;

  const u16* gA[4]; const u16* gB[NB];
  u16* ldsA[4]; u16* ldsB[NB];
  #pragma unroll
  for (int i = 0; i < 4; ++i) {
    gA[i]  = A + (size_t)(row0 + wave * 32 + i * 8 + l8) * K + (l7 ^ l8) * 8;
    ldsA[i] = (u16*)(lds + wave * 4096 + i * 1024);
  }
  #pragma unroll
  for (int i = 0; i < NB; ++i) {
    gB[i]  = Bm + (size_t)(col0 + wave * (BN / 8) + i * 8 + l8) * K + (l7 ^ l8) * 8;
    ldsB[i] = (u16*)(lds + ASZ + wave * (BN * 16) + i * 1024);
  }
  auto stage = [&](int buf, int t) {
    const size_t ko = (size_t)t * 64;
    #pragma unroll
    for (int i = 0; i < 4; ++i)
      gl2lds16(gA[i] + ko, (u16*)((char*)ldsA[i] + buf * BUF));
    #pragma unroll
    for (int i = 0; i < NB; ++i)
      gl2lds16(gB[i] + ko, (u16*)((char*)ldsB[i] + buf * BUF));
  };

  const int colx0 = (((lane >> 4))     ^ l7) * 16;
  const int colx1 = ((4 + (lane >> 4)) ^ l7) * 16;
  const char* aB = lds + (wm * 128 + (lane & 15)) * 128;
  const char* bB = lds + ASZ + (wn * WNC + (lane & 15)) * 128;

  f32x4 acc[8][NF];
  #pragma unroll
  for (int i = 0; i < 8; ++i)
    #pragma unroll
    for (int j = 0; j < NF; ++j) { f32x4 z = {0.f,0.f,0.f,0.f}; acc[i][j] = z; }

  stage(0, 0);
  stage(1, 1);
  vmwait<LOADS>();                        // tile 0 landed (tile 1 in flight)
  __builtin_amdgcn_s_barrier();

  for (int t = 0; t < T; ++t) {
    const int bo = (t & 1) * BUF;
    #pragma unroll
    for (int kh = 0; kh < 2; ++kh) {
      const int cx = kh ? colx1 : colx0;
      bf16x8 bfr[NF];
      #pragma unroll
      for (int nf = 0; nf < NF; ++nf)
        bfr[nf] = *(const bf16x8*)(bB + bo + nf * 2048 + cx);
      #pragma unroll
      for (int mh = 0; mh < 2; ++mh) {
        bf16x8 af[4];
        #pragma unroll
        for (int mf = 0; mf < 4; ++mf)
          af[mf] = *(const bf16x8*)(aB + bo + mh * 8192 + mf * 2048 + cx);
        __builtin_amdgcn_s_barrier();
        asm volatile("s_waitcnt lgkmcnt(0)" ::: "memory");
        __builtin_amdgcn_s_setprio(1);
        #pragma unroll
        for (int mf = 0; mf < 4; ++mf)
          #pragma unroll
          for (int nf = 0; nf < NF; ++nf)
            acc[mh * 4 + mf][nf] = mfma_bf16(af[mf], bfr[nf], acc[mh * 4 + mf][nf]);
        __builtin_amdgcn_s_setprio(0);
        __builtin_amdgcn_s_barrier();
      }
    }
    // tile end: all waves past their reads of buf[t&1] -> refill it
    if (t + 2 < T) stage(t & 1, t + 2);
    if (t + 1 < T) {
      if (t + 2 < T) vmwait<LOADS>();     // tile t+1 landed; t+2 in flight
      else           vmwait<0>();         // tail drain
      __builtin_amdgcn_s_barrier();
    }
  }

  // epilogue: C/D layout row=(l>>4)*4+r, col=l&15 (m89-verified)
  const int mwv = row0 + wm * 128, nwv = col0 + wn * WNC;
  #pragma unroll
  for (int mf8 = 0; mf8 < 8; ++mf8)
    #pragma unroll
    for (int nf = 0; nf < NF; ++nf)
      #pragma unroll
      for (int r = 0; r < 4; ++r) {
        int m = mwv + (mf8 >> 2) * 64 + (mf8 & 3) * 16 + (lane >> 4) * 4 + r;
        int n = nwv + nf * 16 + (lane & 15);
        float v = acc[mf8][nf][r];
        if (BF16OUT) ((u16*)Cp)[(size_t)m * N + n] = f2bf_fast(v);
        else         ((float*)Cp)[(size_t)m * N + n] = v;
      }
}

// ---------------- fused RMSNorm (full row) + partial RoPE + head transpose --
__global__ __launch_bounds__(256) void norm_rope(const u16* __restrict__ qkv,
                                                 const float* __restrict__ cosb,
                                                 const float* __restrict__ sinb,
                                                 const float* __restrict__ qw,
                                                 const float* __restrict__ kw,
                                                 u16* __restrict__ Qo,
                                                 u16* __restrict__ Ko) {
  const int s = blockIdx.x, t = threadIdx.x;
  const int wave = t >> 6, lane = t & 63;
  const float SL = 0.08838834764831845f * 1.4426950408889634f;  // SCALE*log2e
  __shared__ float rowbuf[HIDN];
  __shared__ float red[4];
  const u16* base = qkv + (size_t)s * QKVN;

  float x[8];
  {
    uint4 v = *(const uint4*)(base + t * 8);
    u32 w4[4] = {v.x, v.y, v.z, v.w};
    #pragma unroll
    for (int j = 0; j < 4; ++j) {
      x[2*j]   = bf2f((u16)(w4[j] & 0xffffu));
      x[2*j+1] = bf2f((u16)(w4[j] >> 16));
    }
  }
  float ss = 0.f;
  #pragma unroll
  for (int j = 0; j < 8; ++j) ss += x[j] * x[j];
  #pragma unroll
  for (int m = 1; m < 64; m <<= 1) ss += __shfl_xor(ss, m);
  if (lane == 0) red[wave] = ss;
  __syncthreads();
  float rs = rsqrtf((red[0]+red[1]+red[2]+red[3]) * (1.0f / HIDN) + 1e-6f);
  #pragma unroll
  for (int j = 0; j < 8; ++j) rowbuf[t*8 + j] = x[j] * rs * qw[t*8 + j];
  __syncthreads();
  {
    int i0 = t * 8, d0 = i0 & (HDIM - 1), hh = i0 >> 7;
    float o[8];
    if (d0 < ROTD) {
      #pragma unroll
      for (int j = 0; j < 8; ++j) {
        int d = d0 + j;
        float rot = (d < 32) ? -rowbuf[i0 + j + 32] : rowbuf[i0 + j - 32];
        o[j] = rowbuf[i0 + j] * cosb[s*ROTD + d] + rot * sinb[s*ROTD + d];
      }
    } else {
      #pragma unroll
      for (int j = 0; j < 8; ++j) o[j] = rowbuf[i0 + j];
    }
    uint4 r;
    r.x = (u32)f2bf(o[0]*SL) | ((u32)f2bf(o[1]*SL) << 16);
    r.y = (u32)f2bf(o[2]*SL) | ((u32)f2bf(o[3]*SL) << 16);
    r.z = (u32)f2bf(o[4]*SL) | ((u32)f2bf(o[5]*SL) << 16);
    r.w = (u32)f2bf(o[6]*SL) | ((u32)f2bf(o[7]*SL) << 16);
    *(uint4*)(Qo + ((size_t)hh * S_LEN + s) * HDIM + d0) = r;
  }

  const u16* kbase = base + HIDN;
  float y0, y1;
  { u32 v = *(const u32*)(kbase + t * 2); y0 = bf2f((u16)(v & 0xffffu)); y1 = bf2f((u16)(v >> 16)); }
  float ss2 = y0*y0 + y1*y1;
  #pragma unroll
  for (int m = 1; m < 64; m <<= 1) ss2 += __shfl_xor(ss2, m);
  __syncthreads();
  if (lane == 0) red[wave] = ss2;
  __syncthreads();
  float rs2 = rsqrtf((red[0]+red[1]+red[2]+red[3]) * (1.0f / 512.0f) + 1e-6f);
  rowbuf[t*2]     = y0 * rs2 * kw[t*2];
  rowbuf[t*2 + 1] = y1 * rs2 * kw[t*2 + 1];
  __syncthreads();
  {
    int i0 = t * 2, d0 = i0 & (HDIM - 1), hh = i0 >> 7;
    float o0, o1;
    if (d0 < ROTD) {
      float r0 = (d0 < 32) ? -rowbuf[i0 + 32] : rowbuf[i0 - 32];
      float r1 = (d0 + 1 < 32) ? -rowbuf[i0 + 1 + 32] : rowbuf[i0 + 1 - 32];
      o0 = rowbuf[i0]     * cosb[s*ROTD + d0]     + r0 * sinb[s*ROTD + d0];
      o1 = rowbuf[i0 + 1] * cosb[s*ROTD + d0 + 1] + r1 * sinb[s*ROTD + d0 + 1];
    } else { o0 = rowbuf[i0]; o1 = rowbuf[i0 + 1]; }
    u32 r = (u32)f2bf(o0) | ((u32)f2bf(o1) << 16);
    *(u32*)(Ko + ((size_t)hh * S_LEN + s) * HDIM + d0) = r;
  }
}

// ---------------- V transpose: qkv[S][3072] v-cols -> Vt[NKV][HD][S] --------
__global__ __launch_bounds__(256) void vtrans(const u16* __restrict__ qkv,
                                              u16* __restrict__ Vt) {
  const int sb = blockIdx.x * 64, db = blockIdx.y * 64, kvh = blockIdx.z;
  __shared__ u16 tile[64][72];
  const int t = threadIdx.x;
  {
    int r = t >> 2, cc = (t & 3) * 16;
    const u16* src = qkv + (size_t)(sb + r) * QKVN + 2560 + kvh * HDIM + db + cc;
    *(uint4*)&tile[r][cc]     = *(const uint4*)(src);
    *(uint4*)&tile[r][cc + 8] = *(const uint4*)(src + 8);
  }
  __syncthreads();
  {
    int d = t >> 2, sc = (t & 3) * 16;
    u16 tmp[16];
    #pragma unroll
    for (int j = 0; j < 16; ++j) tmp[j] = tile[sc + j][d];
    u16* dst = Vt + ((size_t)kvh * HDIM + db + d) * S_LEN + sb + sc;
    *(uint4*)dst       = *(uint4*)&tmp[0];
    *(uint4*)(dst + 8) = *(uint4*)&tmp[8];
  }
}

// ---------------- causal GQA flash attention (v7, unchanged from R12) -------
__global__ __launch_bounds__(256, 2) void attn_fwd(const u16* __restrict__ Q,
                                                   const u16* __restrict__ K,
                                                   const u16* __restrict__ Vt,
                                                   u16* __restrict__ O) {
  const int n    = blockIdx.x;
  const int slot = n & 7, kq = n >> 3;             // kq 0..63
  const int kvh  = slot >> 1;                      // XCD affinity: 2 slots/kvh
  const int h    = kvh * 4 + (slot & 1) * 2 + (kq & 1);
  const int p    = kq >> 1;                        // mirror-pair index 0..31
  const int tid = threadIdx.x, wave = tid >> 6, lane = tid & 63;
  const int rh   = wave & 1;                       // row-half of the q tile
  const int kvh2 = wave >> 1;                      // kv-half of the kv tile
  __shared__ u16 Ks[2][64][128];                   // 32KB
  __shared__ u16 Vs[2][128][64];                   // 32KB
  __shared__ u16 Ps[2][32][64];                    //  8KB (per row-half)

  const u16* gKb[4]; const u16* gVb[4];
  #pragma unroll
  for (int i = 0; i < 4; ++i) {
    int cc = wave * 4 + i;
    int rk = cc * 4 + (lane >> 4);
    gKb[i] = K + ((size_t)kvh * S_LEN + rk) * HDIM + ((lane & 15) ^ (rk & 7)) * 8;
    int rv = cc * 8 + (lane >> 3);
    gVb[i] = Vt + ((size_t)kvh * HDIM + rv) * S_LEN + ((lane & 7) ^ (rv & 7)) * 8;
  }
  auto stage = [&](int buf, int kvb) {
    #pragma unroll
    for (int i = 0; i < 4; ++i) {
      int cc = wave * 4 + i;
      gl2lds16(gKb[i] + (size_t)kvb * HDIM, &Ks[buf][cc * 4][0]);
      gl2lds16(gVb[i] + kvb,                &Vs[buf][cc * 8][0]);
    }
  };

  int offv[4];
  #pragma unroll
  for (int kk = 0; kk < 4; ++kk)
    offv[kk] = (kk * 64 + (lane >> 4) * 16) ^ ((lane & 7) << 4);
  const char* ksB = (const char*)Ks + kvh2 * 8192 + (lane & 15) * 256;
  const char* vsB = (const char*)Vs + (lane & 15) * 128;
  const char* psB = (const char*)Ps + rh * 4096 + (lane & 15) * 128;
  char*       pwB = (char*)Ps + rh * 4096;
  const int   lx2 = (lane & 15) * 2;
  const int   vko = offv[kvh2];                    // vf/pf col offset (kv half)

  stage(0, 0);                                     // prologue: job0 tile0
  __syncthreads();
  int cur = 0;

  for (int job = 0; job < 2; ++job) {
    const int qb = job ? (63 - p) : p;
    const int ntiles = qb + 1;
    const int qg0 = qb * 64 + rh * 32 + (lane >> 4) * 4;  // + qm*16 + r = q row

    bf16x8 qf[2][4];
    #pragma unroll
    for (int qm = 0; qm < 2; ++qm) {
      const u16* qptr = Q + ((size_t)h * S_LEN + qb * 64 + rh * 32 + qm * 16 + (lane & 15)) * HDIM
                        + (lane >> 4) * 8;
      #pragma unroll
      for (int kk = 0; kk < 4; ++kk) qf[qm][kk] = *(const bf16x8*)(qptr + kk * 32);
    }

    float lsum[2][4];
    #pragma unroll
    for (int qm = 0; qm < 2; ++qm)
      #pragma unroll
      for (int r = 0; r < 4; ++r) lsum[qm][r] = 0.f;
    f32x4 o[2][8];
    #pragma unroll
    for (int qm = 0; qm < 2; ++qm)
      #pragma unroll
      for (int i = 0; i < 8; ++i) { f32x4 z = {0.f,0.f,0.f,0.f}; o[qm][i] = z; }

    for (int kt = 0; kt < ntiles; ++kt) {
      if (kt + 1 < ntiles)      stage(cur ^ 1, (kt + 1) * 64);
      else if (job == 0)        stage(cur ^ 1, 0);

      const int bufo = cur << 14;
      const bool diag = (kt == ntiles - 1);

      if (!(diag && kvh2 == 1 && rh == 0)) {
        f32x4 sc[2][2];
        #pragma unroll
        for (int qm = 0; qm < 2; ++qm)
          #pragma unroll
          for (int i = 0; i < 2; ++i) { f32x4 z = {0.f,0.f,0.f,0.f}; sc[qm][i] = z; }
        __builtin_amdgcn_s_setprio(1);
        #pragma unroll
        for (int kk = 0; kk < 4; ++kk)
          #pragma unroll
          for (int nf = 0; nf < 2; ++nf) {
            bf16x8 kf = *(const bf16x8*)(ksB + bufo + nf * 4096 + offv[kk]);
            sc[0][nf] = mfma_bf16(qf[0][kk], kf, sc[0][nf]);
            sc[1][nf] = mfma_bf16(qf[1][kk], kf, sc[1][nf]);
          }
        __builtin_amdgcn_s_setprio(0);

        if (diag) {
          const int kvb = kt * 64;
          #pragma unroll
          for (int qm = 0; qm < 2; ++qm)
            #pragma unroll
            for (int nf = 0; nf < 2; ++nf) {
              int col = kvb + kvh2 * 32 + nf * 16 + (lane & 15);
              #pragma unroll
              for (int r = 0; r < 4; ++r) {
                float e = __builtin_amdgcn_exp2f(sc[qm][nf][r]);
                e = (col <= qg0 + qm * 16 + r) ? e : 0.f;
                sc[qm][nf][r] = e;
                lsum[qm][r] += e;
              }
            }
        } else {
          #pragma unroll
          for (int qm = 0; qm < 2; ++qm)
            #pragma unroll
            for (int nf = 0; nf < 2; ++nf)
              #pragma unroll
              for (int r = 0; r < 4; ++r) {
                float e = __builtin_amdgcn_exp2f(sc[qm][nf][r]);
                sc[qm][nf][r] = e;
                lsum[qm][r] += e;
              }
        }

        #pragma unroll
        for (int qm = 0; qm < 2; ++qm)
          #pragma unroll
          for (int nf = 0; nf < 2; ++nf)
            #pragma unroll
            for (int r = 0; r < 4; ++r) {
              int prow = qm * 16 + (lane >> 4) * 4 + r;
              int bcol = (kvh2 * 64 + nf * 32 + lx2) ^ ((prow & 7) << 4);
              *(u16*)(pwB + prow * 128 + bcol) = f2bf_fast(sc[qm][nf][r]);
            }

        bf16x8 pf0, pf1;
        pf0 = *(const bf16x8*)(psB + vko);
        pf1 = *(const bf16x8*)(psB + 2048 + vko);
        __builtin_amdgcn_s_setprio(1);
        #pragma unroll
        for (int nf2 = 0; nf2 < 8; ++nf2) {
          bf16x8 vf = *(const bf16x8*)(vsB + bufo + nf2 * 2048 + vko);
          o[0][nf2] = mfma_bf16(pf0, vf, o[0][nf2]);
          o[1][nf2] = mfma_bf16(pf1, vf, o[1][nf2]);
        }
        __builtin_amdgcn_s_setprio(0);
      }

      __syncthreads();
      cur ^= 1;
    }

    // ---- cross-kv-half combine (partials exactly additive) ----
    {
      f32x4* scr = (f32x4*)((rh == 0) ? (char*)Ks + (cur ^ 1) * 16384
                                      : (char*)Vs + (cur ^ 1) * 16384);
      float* lsc = (float*)Ps;
      if (kvh2 == 1) {
        #pragma unroll
        for (int qm = 0; qm < 2; ++qm)
          #pragma unroll
          for (int nf2 = 0; nf2 < 8; ++nf2)
            scr[(qm * 8 + nf2) * 64 + lane] = o[qm][nf2];
        #pragma unroll
        for (int qm = 0; qm < 2; ++qm)
          #pragma unroll
          for (int r = 0; r < 4; ++r)
            lsc[rh * 512 + (qm * 4 + r) * 64 + lane] = lsum[qm][r];
      }
      __syncthreads();
      if (kvh2 == 0) {
        #pragma unroll
        for (int qm = 0; qm < 2; ++qm)
          #pragma unroll
          for (int nf2 = 0; nf2 < 8; ++nf2)
            o[qm][nf2] += scr[(qm * 8 + nf2) * 64 + lane];
        #pragma unroll
        for (int qm = 0; qm < 2; ++qm)
          #pragma unroll
          for (int r = 0; r < 4; ++r)
            lsum[qm][r] += lsc[rh * 512 + (qm * 4 + r) * 64 + lane];

        #pragma unroll
        for (int qm = 0; qm < 2; ++qm)
          #pragma unroll
          for (int r = 0; r < 4; ++r) {
            float lt = lsum[qm][r];
            #pragma unroll
            for (int m = 1; m < 16; m <<= 1) lt += __shfl_xor(lt, m);
            float inv = 1.f / lt;
            int srow = qg0 + qm * 16 + r;
            #pragma unroll
            for (int nf2 = 0; nf2 < 8; ++nf2) {
              int col = h * HDIM + nf2 * 16 + (lane & 15);
              O[(size_t)srow * HIDN + col] = f2bf_fast(o[qm][nf2][r] * inv);
            }
          }
      }
      __syncthreads();
    }
  }
}

// ---------------- launch -----------------------------------------------------
extern "C" void kernel_launch(void* const* d_in, const int* in_sizes, int n_in,
                              void* d_out, int out_size, void* d_ws, size_t ws_size,
                              hipStream_t stream) {
  (void)in_sizes; (void)n_in; (void)out_size; (void)ws_size;
  const float* h    = (const float*)d_in[0];
  const float* cosb = (const float*)d_in[1];
  const float* sinb = (const float*)d_in[2];
  const float* Wq   = (const float*)d_in[3];
  const float* Wk   = (const float*)d_in[4];
  const float* Wv   = (const float*)d_in[5];
  const float* Wo   = (const float*)d_in[6];
  const float* qw   = (const float*)d_in[7];
  const float* kw   = (const float*)d_in[8];
  float* out = (float*)d_out;

  char* ws = (char*)d_ws;
  u16* hbf  = (u16*)(ws);
  u16* Kb   = (u16*)(ws + (16u << 20));
  u16* Vtb  = (u16*)(ws + (20u << 20));
  u16* wqkv = (u16*)(ws + (24u << 20));
  u16* Qb   = (u16*)(ws + (24u << 20));
  u16* qkvb = (u16*)(ws + (40u << 20));
  u16* wob  = (u16*)(ws + (40u << 20));

  cvt4_f32_bf16<<<7168, 256, 0, stream>>>(h, Wq, Wk, Wv, hbf, wqkv);

  gemm_big<192, 3, true><<<dim3(16, 16), 512, 0, stream>>>(hbf, wqkv, qkvb,
                                                           4096, 3072, 2048);

  norm_rope<<<4096, 256, 0, stream>>>(qkvb, cosb, sinb, qw, kw, Qb, Kb);
  vtrans<<<dim3(64, 2, 4), 256, 0, stream>>>(qkvb, Vtb);

  cvt_f32_bf16<<<2048, 256, 0, stream>>>(Wo, wob);

  attn_fwd<<<dim3(512), 256, 0, stream>>>(Qb, Kb, Vtb, hbf);

  gemm_big<128, 2, false><<<dim3(16, 16), 512, 0, stream>>>(hbf, wob, out,
                                                            4096, 2048, 2048);
}